// Round 22
// baseline (241.936 us; speedup 1.0000x reference)
//
#include <hip/hip_runtime.h>
#include <hip/hip_bf16.h>

#define NB 2
#define NC 64
#define NHW 4096
#define NPIX (NB*NHW)          // 8192
#define SZ   (NB*NC*NHW)       // 524288 floats per 64-ch fp32 tensor
#define LOG2E 1.4426950408889634f

typedef __attribute__((ext_vector_type(8))) short bf16x8;
typedef __attribute__((ext_vector_type(4))) float f32x4;
typedef __hip_bfloat16 hbf;

__device__ __forceinline__ float clamp01(float v){ return fminf(fmaxf(v, 0.f), 1.f); }
__device__ __forceinline__ float fexp2(float x){ return __builtin_amdgcn_exp2f(x); }  // raw v_exp_f32

// ---------------------------------------------------------------- reductions
__global__ __launch_bounds__(256) void k_max_hw(const float* __restrict__ in, float* __restrict__ mx){
  int bc = blockIdx.x; int t = threadIdx.x;
  const float* p = in + (size_t)bc*NHW;
  float m = -1e30f;
  for (int n = t; n < NHW; n += 256) m = fmaxf(m, p[n]);
  #pragma unroll
  for (int off = 32; off; off >>= 1) m = fmaxf(m, __shfl_xor(m, off));
  __shared__ float sm[4];
  if ((t & 63) == 0) sm[t >> 6] = m;
  __syncthreads();
  if (t == 0) mx[bc] = fmaxf(fmaxf(sm[0], sm[1]), fmaxf(sm[2], sm[3]));
}

__global__ __launch_bounds__(256) void k_chmean(const float* __restrict__ in, float* __restrict__ out){
  int p = blockIdx.x*256 + threadIdx.x;         // 0..8191
  int b = p >> 12, n = p & 4095;
  const float* base = in + (size_t)b*NC*NHW + n;
  float s = 0.f;
  #pragma unroll
  for (int c = 0; c < 64; ++c) s += base[c*NHW];
  out[p] = s * (1.0f/64.0f);
}

// ---------------------------------------------------------------- both depthwise 3x3 branches + score MLPs, one launch
__global__ __launch_bounds__(256) void k_dw3b(const float* __restrict__ hsi0, const float* __restrict__ wh,
    const float* __restrict__ bh, const float* __restrict__ mxb,
    const float* __restrict__ spe_w, const float* __restrict__ spe_b,
    const float* __restrict__ msi0, const float* __restrict__ wm, const float* __restrict__ bm,
    const float* __restrict__ cmb, const float* __restrict__ spw, const float* __restrict__ spb,
    float* __restrict__ out0, float* __restrict__ out1){
  int bb = blockIdx.x;                    // 0..4095
  int br = bb >= (SZ/256);                // scalar branch
  int bbl = br ? bb - SZ/256 : bb;        // 0..2047
  int b = bbl >> 10;                      // scalar
  int c = (bbl >> 4) & 63;                // scalar
  int t = threadIdx.x;
  int pix = (bbl & 15)*256 + t;
  const float* in = br ? msi0 : hsi0;
  const float* w  = br ? wm : wh;
  const float* bs = br ? bm : bh;
  float* out      = br ? out1 : out0;
  int y = pix >> 6, x = pix & 63;
  const float* base = in + (size_t)(b*64 + c)*NHW;
  float wf[9];
  #pragma unroll
  for (int i = 0; i < 9; ++i) wf[i] = w[c*9 + i];
  float acc = 0.f;
  #pragma unroll
  for (int ky = -1; ky <= 1; ++ky){
    int yy = y + ky; if ((unsigned)yy >= 64u) continue;
    #pragma unroll
    for (int kx = -1; kx <= 1; ++kx){
      int xx = x + kx; if ((unsigned)xx >= 64u) continue;
      acc += base[yy*64 + xx] * wf[(ky+1)*3 + (kx+1)];
    }
  }
  acc += bs[c];
  if (!br){
    float spe = spe_b[c];
    #pragma unroll 8
    for (int i = 0; i < 64; ++i) spe += spe_w[c*64 + i] * mxb[b*64 + i];
    acc += clamp01(spe);
  } else {
    float z = spw[c] * cmb[b*4096 + pix] + spb[c];
    acc += clamp01(z);
  }
  out[(size_t)(b*64 + c)*NHW + pix] = acc;
}

// ---------------------------------------------------------------- lean simple pw body (64->64, flat args)
__device__ __forceinline__ void pw_simple(const float* __restrict__ in, const float* __restrict__ w,
    const float* __restrict__ bias, float* __restrict__ outf,
    hbf* __restrict__ tq, float tscale, hbf* __restrict__ cq, int ptile){
  __shared__ __align__(16) float Xs[64][32];
  __shared__ __align__(16) float Wt[64][64];    // [i][o]
  int t = threadIdx.x;
  int b = ptile >> 7; int n0 = (ptile & 127)*32;
  const float* inb = in + (size_t)b*64*NHW + n0;
  #pragma unroll
  for (int k = 0; k < 8; ++k){
    int i = k*8 + (t >> 5); int n = t & 31;
    Xs[i][n] = inb[(size_t)i*NHW + n];
  }
  #pragma unroll
  for (int k = 0; k < 16; ++k){
    int idx = k*256 + t; int o = idx & 63, i = idx >> 6;
    Wt[i][o] = w[(size_t)o*64 + i];
  }
  __syncthreads();
  int tn = t & 15, to = t >> 4;
  float a0x=0,a0y=0,a1x=0,a1y=0,a2x=0,a2y=0,a3x=0,a3y=0;
  #pragma unroll
  for (int i = 0; i < 64; ++i){
    const float2 xv = *(const float2*)&Xs[i][tn*2];
    const float4 wv = *(const float4*)&Wt[i][to*4];
    a0x += wv.x*xv.x; a0y += wv.x*xv.y;
    a1x += wv.y*xv.x; a1y += wv.y*xv.y;
    a2x += wv.z*xv.x; a2y += wv.z*xv.y;
    a3x += wv.w*xv.x; a3y += wv.w*xv.y;
  }
  float ax[4] = {a0x,a1x,a2x,a3x}, ay[4] = {a0y,a1y,a2y,a3y};
  #pragma unroll
  for (int oo = 0; oo < 4; ++oo){
    int o = to*4 + oo;
    float bv = bias[o];
    size_t obase = ((size_t)b*64 + o)*NHW + n0 + tn*2;
    float v0 = ax[oo] + bv, v1 = ay[oo] + bv;
    if (tq){
      int h = o >> 4, d = o & 15;
      size_t tb = ((size_t)(b*4 + h)*4096 + n0 + tn*2)*16 + d;
      tq[tb]    = __float2bfloat16(v0*tscale);
      tq[tb+16] = __float2bfloat16(v1*tscale);
    }
    if (cq){
      cq[obase+0] = __float2bfloat16(v0);
      cq[obase+1] = __float2bfloat16(v1);
    }
    if (outf){
      float2 vv; vv.x = v0; vv.y = v1;
      *(float2*)(outf + obase) = vv;
    }
  }
}

// two branch 1x1 convs in one launch: grid (256,1,2), flat args, scalar z-select
__global__ __launch_bounds__(256) void k_pwbr(const float* __restrict__ t1, const float* __restrict__ w0,
    const float* __restrict__ b0, float* __restrict__ hb,
    const float* __restrict__ tm, const float* __restrict__ w1,
    const float* __restrict__ b1, float* __restrict__ mb){
  int z = blockIdx.z;
  const float* in = z ? tm : t1;
  const float* w  = z ? w1 : w0;
  const float* bs = z ? b1 : b0;
  float* out      = z ? mb : hb;
  pw_simple(in, w, bs, out, nullptr, 1.f, nullptr, blockIdx.x);
}

// Q,K,V projections in one launch: grid (256,1,3), flat args, scalar z-select
__global__ __launch_bounds__(256) void k_pwqkv(const float* __restrict__ mb, const float* __restrict__ hb,
    const float* __restrict__ qw, const float* __restrict__ qb,
    const float* __restrict__ kw, const float* __restrict__ kb,
    const float* __restrict__ vw, const float* __restrict__ vb,
    hbf* __restrict__ qt, hbf* __restrict__ kt, hbf* __restrict__ vbf, float qs){
  int z = blockIdx.z;
  const float* in = (z == 0) ? mb : hb;
  const float* w  = (z == 0) ? qw : ((z == 1) ? kw : vw);
  const float* bs = (z == 0) ? qb : ((z == 1) ? kb : vb);
  hbf* tq = (z == 0) ? qt : ((z == 1) ? kt : nullptr);
  float ts = (z == 0) ? qs : 1.f;
  hbf* cq = (z == 2) ? vbf : nullptr;
  pw_simple(in, w, bs, nullptr, tq, ts, cq, blockIdx.x);
}

// ---------------------------------------------------------------- full-featured pw body (flat args)
// no-max flash combine: v = (sum_c Pacc_c) / (sum_c Pl_c)
__device__ __forceinline__ void pw_full(const float* __restrict__ in, const float* __restrict__ w,
    const float* __restrict__ bias, const float* __restrict__ lnw,
    const float* __restrict__ in2, float* __restrict__ add_out,
    const float* __restrict__ r1, const float* __restrict__ r2,
    float* __restrict__ outf, int OC,
    const float* __restrict__ Pacc, const float* __restrict__ Pl,
    int ptile, int oc0){
  __shared__ __align__(16) float Xs[64][32];
  __shared__ __align__(16) float Wt[64][64];    // [i][o]
  __shared__ float psum[8][32], psqs[8][32];
  __shared__ float invs[32];
  __shared__ float fs[4][32];                   // [h][n] 1/L
  int t = threadIdx.x;
  int b = ptile >> 7; int n0 = (ptile & 127)*32;
  const float* inb = in ? in + (size_t)b*64*NHW + n0 : nullptr;
  const float* inb2 = in2 ? in2 + (size_t)b*64*NHW + n0 : nullptr;
  float* aob = add_out ? add_out + (size_t)b*64*NHW + n0 : nullptr;
  if (Pacc){
    if (t < 128){
      int h = t >> 5, n = t & 31;
      int bh = b*4 + h, q = n0 + n;
      float L = Pl[(size_t)bh*4096 + q] + Pl[(size_t)(8+bh)*4096 + q]
              + Pl[(size_t)(16+bh)*4096 + q] + Pl[(size_t)(24+bh)*4096 + q];
      fs[h][n] = 1.0f / L;
    }
    __syncthreads();
  }
  float ps = 0.f, pss = 0.f;
  #pragma unroll
  for (int k = 0; k < 8; ++k){
    int i = k*8 + (t >> 5); int n = t & 31;
    float v;
    if (Pacc){
      int h = i >> 4, d = i & 15, bh = b*4 + h;
      const float* pb = Pacc + ((size_t)(bh*16 + d))*4096 + n0 + n;
      v = (pb[0] + pb[(size_t)SZ] + pb[(size_t)2*SZ] + pb[(size_t)3*SZ]) * fs[h][n];
    } else {
      v = inb[(size_t)i*NHW + n];
      if (inb2) v += inb2[(size_t)i*NHW + n];
    }
    Xs[i][n] = v;
    if (aob && oc0 == 0) aob[(size_t)i*NHW + n] = v;
    ps += v; pss += v*v;
  }
  if (lnw){ psum[t>>5][t&31] = ps; psqs[t>>5][t&31] = pss; }
  #pragma unroll
  for (int k = 0; k < 16; ++k){
    int idx = k*256 + t; int o = idx & 63, i = idx >> 6;
    float wv = w[(size_t)(oc0 + o)*64 + i];
    if (lnw) wv *= lnw[i];
    Wt[i][o] = wv;
  }
  __syncthreads();
  if (lnw){
    if (t < 32){
      float s1 = 0.f, s2 = 0.f;
      #pragma unroll
      for (int g = 0; g < 8; ++g){ s1 += psum[g][t]; s2 += psqs[g][t]; }
      float mu = s1*(1.0f/64.0f);
      float var = s2*(1.0f/64.0f) - mu*mu;
      invs[t] = rsqrtf(fmaxf(var, 0.f) + 1e-5f);
    }
    __syncthreads();
  }
  int tn = t & 15, to = t >> 4;
  float a0x=0,a0y=0,a1x=0,a1y=0,a2x=0,a2y=0,a3x=0,a3y=0;
  #pragma unroll
  for (int i = 0; i < 64; ++i){
    const float2 xv = *(const float2*)&Xs[i][tn*2];
    const float4 wv = *(const float4*)&Wt[i][to*4];
    a0x += wv.x*xv.x; a0y += wv.x*xv.y;
    a1x += wv.y*xv.x; a1y += wv.y*xv.y;
    a2x += wv.z*xv.x; a2y += wv.z*xv.y;
    a3x += wv.w*xv.x; a3y += wv.w*xv.y;
  }
  float sx = 1.f, sy = 1.f;
  if (lnw){ sx = invs[tn*2+0]; sy = invs[tn*2+1]; }
  float ax[4] = {a0x,a1x,a2x,a3x}, ay[4] = {a0y,a1y,a2y,a3y};
  #pragma unroll
  for (int oo = 0; oo < 4; ++oo){
    int o = oc0 + to*4 + oo;
    float bv = bias ? bias[o] : 0.f;
    size_t obase = ((size_t)b*OC + o)*NHW + n0 + tn*2;
    float v0 = ax[oo]*sx + bv, v1 = ay[oo]*sy + bv;
    if (r1){ v0 += r1[obase+0]; v1 += r1[obase+1]; }
    if (r2){ v0 += r2[obase+0]; v1 += r2[obase+1]; }
    if (outf){
      float2 vv; vv.x = v0; vv.y = v1;
      *(float2*)(outf + obase) = vv;
    }
  }
}

__global__ __launch_bounds__(256) void k_pw(const float* __restrict__ in, const float* __restrict__ w,
    const float* __restrict__ bias, const float* __restrict__ lnw,
    const float* __restrict__ in2, float* __restrict__ add_out,
    const float* __restrict__ r1, const float* __restrict__ r2,
    float* __restrict__ outf, int OC,
    const float* __restrict__ Pacc, const float* __restrict__ Pl){
  pw_full(in, w, bias, lnw, in2, add_out, r1, r2, outf, OC, Pacc, Pl, blockIdx.x, blockIdx.y*64);
}

// spectral ffn_in (z=0, OC=128) || restormer qkv (z=1, OC=192): grid (256,3,2)
__global__ __launch_bounds__(256) void k_pwfi(const float* __restrict__ xb, const float* __restrict__ w0,
    const float* __restrict__ ln0, float* __restrict__ tb,
    const float* __restrict__ hb, const float* __restrict__ w1, const float* __restrict__ ln1,
    const float* __restrict__ mb, float* __restrict__ yb, float* __restrict__ tb2){
  int z = blockIdx.z;
  int OC = z ? 192 : 128;
  int oc0 = blockIdx.y*64;
  if (oc0 >= OC) return;
  const float* in  = z ? hb : xb;
  const float* w   = z ? w1 : w0;
  const float* lnw = z ? ln1 : ln0;
  const float* in2 = z ? mb : nullptr;
  float* aout      = z ? yb : nullptr;
  float* outf      = z ? tb2 : tb;
  pw_full(in, w, nullptr, lnw, in2, aout, nullptr, nullptr, outf, OC, nullptr, nullptr, blockIdx.x, oc0);
}

// spectral ffn_out (blocks 0..255) || restormer rnorm (blocks 256..511)
__global__ __launch_bounds__(256) void k_pwrn(const float* __restrict__ g1, const float* __restrict__ w,
    const float* __restrict__ xb, float* __restrict__ xout,
    const float* __restrict__ qkv, float* __restrict__ norms){
  int bb = blockIdx.x;
  if (bb < NPIX/32){
    pw_full(g1, w, nullptr, nullptr, nullptr, nullptr, xb, nullptr, xout, 64, nullptr, nullptr, bb, 0);
  } else {
    int blk = bb - NPIX/32; int b = blk >> 7, r = blk & 127;
    int t = threadIdx.x;
    const float* p = qkv + ((size_t)b*192 + r)*NHW;
    float ss = 0.f;
    for (int i = t*4; i < NHW; i += 1024){
      float4 v = *(const float4*)(p + i);
      ss += v.x*v.x + v.y*v.y + v.z*v.z + v.w*v.w;
    }
    #pragma unroll
    for (int off = 32; off; off >>= 1) ss += __shfl_xor(ss, off);
    __shared__ float sm[4];
    if ((t & 63) == 0) sm[t >> 6] = ss;
    __syncthreads();
    if (t == 0) norms[blk] = fmaxf(sqrtf(sm[0]+sm[1]+sm[2]+sm[3]), 1e-12f);
  }
}

// ---------------------------------------------------------------- MFMA flash cross-attention, hd=16, n=4096
// grid 2048 = qt(64) x bh(8) x chunk(4); block 256 = 4 waves; wave = 16 queries.
// No-max softmax (Qt pre-scaled 0.25*log2e). Unroll-2 with DUAL accumulators:
// breaks the PV serial chain; 6 loads in flight per iteration pair.
__global__ __launch_bounds__(256) void k_mfa(const hbf* __restrict__ Qt, const hbf* __restrict__ Kt,
                                             const hbf* __restrict__ Vb, float* __restrict__ Pacc,
                                             float* __restrict__ Pl){
  int blk = blockIdx.x;
  int qt = blk & 63; int bh = (blk >> 6) & 7; int c = blk >> 9;   // c 0..3
  int t = threadIdx.x;
  int w = t >> 6, l = t & 63;
  int lg = l >> 4, lq = l & 15;
  int q0 = qt*64 + w*16;
  int rho = ((lq >> 2) << 3) + (lq & 3);        // 0-3,8-11,16-19,24-27
  bf16x8 qf = {};
  if (lg < 2) qf = *(const bf16x8*)&Qt[((size_t)bh*4096 + q0 + lq)*16 + lg*8];
  f32x4 acc0 = {0.f, 0.f, 0.f, 0.f};
  f32x4 acc1 = {0.f, 0.f, 0.f, 0.f};
  float lsum = 0.f;
  const hbf* Ktb = Kt + ((size_t)bh*4096 + c*1024)*16;
  const hbf* Vbb = Vb + (size_t)bh*16*4096 + c*1024;
  for (int kb = 0; kb < 1024; kb += 64){
    bf16x8 kf0a = {}, kf1a = {}, kf0b = {}, kf1b = {};
    if (lg < 2){
      kf0a = *(const bf16x8*)&Ktb[(size_t)(kb + rho)*16 + lg*8];
      kf1a = *(const bf16x8*)&Ktb[(size_t)(kb + rho + 4)*16 + lg*8];
      kf0b = *(const bf16x8*)&Ktb[(size_t)(kb + 32 + rho)*16 + lg*8];
      kf1b = *(const bf16x8*)&Ktb[(size_t)(kb + 32 + rho + 4)*16 + lg*8];
    }
    bf16x8 vfa = *(const bf16x8*)&Vbb[(size_t)lq*4096 + kb + lg*8];
    bf16x8 vfb = *(const bf16x8*)&Vbb[(size_t)lq*4096 + kb + 32 + lg*8];
    f32x4 z = {0.f, 0.f, 0.f, 0.f};
    f32x4 s0a = __builtin_amdgcn_mfma_f32_16x16x32_bf16(kf0a, qf, z, 0, 0, 0);
    f32x4 s1a = __builtin_amdgcn_mfma_f32_16x16x32_bf16(kf1a, qf, z, 0, 0, 0);
    f32x4 s0b = __builtin_amdgcn_mfma_f32_16x16x32_bf16(kf0b, qf, z, 0, 0, 0);
    f32x4 s1b = __builtin_amdgcn_mfma_f32_16x16x32_bf16(kf1b, qf, z, 0, 0, 0);
    float pa[8], pb[8];
    pa[0]=s0a[0]; pa[1]=s0a[1]; pa[2]=s0a[2]; pa[3]=s0a[3];
    pa[4]=s1a[0]; pa[5]=s1a[1]; pa[6]=s1a[2]; pa[7]=s1a[3];
    pb[0]=s0b[0]; pb[1]=s0b[1]; pb[2]=s0b[2]; pb[3]=s0b[3];
    pb[4]=s1b[0]; pb[5]=s1b[1]; pb[6]=s1b[2]; pb[7]=s1b[3];
    #pragma unroll
    for (int i = 0; i < 8; ++i){ pa[i] = fexp2(pa[i]); lsum += pa[i]; }
    #pragma unroll
    for (int i = 0; i < 8; ++i){ pb[i] = fexp2(pb[i]); lsum += pb[i]; }
    bf16x8 pfa, pfb;
    #pragma unroll
    for (int j = 0; j < 8; ++j){
      hbf ha = __float2bfloat16(pa[j]);
      pfa[j] = *reinterpret_cast<short*>(&ha);
      hbf hb2 = __float2bfloat16(pb[j]);
      pfb[j] = *reinterpret_cast<short*>(&hb2);
    }
    acc0 = __builtin_amdgcn_mfma_f32_16x16x32_bf16(vfa, pfa, acc0, 0, 0, 0);
    acc1 = __builtin_amdgcn_mfma_f32_16x16x32_bf16(vfb, pfb, acc1, 0, 0, 0);
  }
  acc0[0] += acc1[0]; acc0[1] += acc1[1]; acc0[2] += acc1[2]; acc0[3] += acc1[3];
  // reduce per-lane lsum across the 4 lane groups (same query lq)
  lsum += __shfl_xor(lsum, 16);
  lsum += __shfl_xor(lsum, 32);
  int pb_ = c*8 + bh;
  if (lg == 0) Pl[(size_t)pb_*4096 + q0 + lq] = lsum;
  #pragma unroll
  for (int r = 0; r < 4; ++r){
    int d = lg*4 + r;
    Pacc[((size_t)pb_*16 + d)*4096 + q0 + lq] = acc0[r];
  }
}

// ---------------------------------------------------------------- FFN dw3x3 + chunk + gelu gate (128->64)
__device__ __forceinline__ void dwgate_body(const float* __restrict__ in, const float* __restrict__ w,
                                            float* __restrict__ out, int g){
  int pix = g & 4095; int c = (g >> 12) & 63; int b = g >> 18;
  int y = pix >> 6, x = pix & 63;
  const float* p1 = in + ((size_t)b*128 + c)*NHW;
  const float* p2 = in + ((size_t)b*128 + 64 + c)*NHW;
  float w1[9], w2[9];
  #pragma unroll
  for (int i = 0; i < 9; ++i){ w1[i] = w[c*9+i]; w2[i] = w[(64+c)*9+i]; }
  float a = 0.f, bb = 0.f;
  #pragma unroll
  for (int ky = -1; ky <= 1; ++ky){
    int yy = y + ky; if ((unsigned)yy >= 64u) continue;
    #pragma unroll
    for (int kx = -1; kx <= 1; ++kx){
      int xx = x + kx; if ((unsigned)xx >= 64u) continue;
      int off = yy*64 + xx; int wi = (ky+1)*3 + (kx+1);
      a  += p1[off]*w1[wi];
      bb += p2[off]*w2[wi];
    }
  }
  float gl = 0.5f*a*(1.0f + erff(a*0.70710678118654752f));   // exact gelu
  out[g] = gl*bb;
}

__global__ __launch_bounds__(256) void k_dwgate(const float* __restrict__ in, const float* __restrict__ w,
                                                float* __restrict__ out){
  dwgate_body(in, w, out, blockIdx.x*256 + threadIdx.x);
}

// dwgate (spectral) || dw192 (restormer qkv) in one launch, scalar block split
__global__ __launch_bounds__(256) void k_dwg2(const float* __restrict__ inG, const float* __restrict__ wG,
                                              float* __restrict__ outG,
                                              const float* __restrict__ inD, const float* __restrict__ wD,
                                              float* __restrict__ outD){
  int bb = blockIdx.x;
  if (bb < SZ/256){
    dwgate_body(inG, wG, outG, bb*256 + threadIdx.x);
  } else {
    int g = (bb - SZ/256)*256 + threadIdx.x;    // B*192*4096
    int pix = g & 4095; int bc = g >> 12; int c = bc % 192;
    int y = pix >> 6, x = pix & 63;
    const float* p = inD + (size_t)bc*NHW;
    float wf[9];
    #pragma unroll
    for (int i = 0; i < 9; ++i) wf[i] = wD[c*9+i];
    float acc = 0.f;
    #pragma unroll
    for (int ky = -1; ky <= 1; ++ky){
      int yy = y + ky; if ((unsigned)yy >= 64u) continue;
      #pragma unroll
      for (int kx = -1; kx <= 1; ++kx){
        int xx = x + kx; if ((unsigned)xx >= 64u) continue;
        acc += p[yy*64 + xx]*wf[(ky+1)*3 + (kx+1)];
      }
    }
    outD[g] = acc;
  }
}

// ---------------------------------------------------------------- restormer channel attention
__global__ __launch_bounds__(256) void k_rattn2(const float* __restrict__ qkv, const float* __restrict__ norms,
                                                const float* __restrict__ temp, float* __restrict__ out){
  int blk = blockIdx.x; int rq = blk & 15, h = (blk >> 4) & 3, b = blk >> 6;
  int t = threadIdx.x;
  const float* bq = qkv + ((size_t)b*192 + h*16 + rq)*NHW;
  const float* bk = qkv + ((size_t)b*192 + 64 + h*16)*NHW;
  float p[16];
  #pragma unroll
  for (int rk = 0; rk < 16; ++rk) p[rk] = 0.f;
  for (int n = t*4; n < NHW; n += 1024){
    float4 qv4 = *(const float4*)(bq + n);
    #pragma unroll
    for (int rk = 0; rk < 16; ++rk){
      float4 kv = *(const float4*)(bk + (size_t)rk*NHW + n);
      p[rk] += qv4.x*kv.x + qv4.y*kv.y + qv4.z*kv.z + qv4.w*kv.w;
    }
  }
  #pragma unroll
  for (int rk = 0; rk < 16; ++rk)
    #pragma unroll
    for (int off = 32; off; off >>= 1) p[rk] += __shfl_xor(p[rk], off);
  __shared__ float red[4][16];
  if ((t & 63) == 0){
    int wv_ = t >> 6;
    #pragma unroll
    for (int rk = 0; rk < 16; ++rk) red[wv_][rk] = p[rk];
  }
  __syncthreads();
  __shared__ float attn[16];
  if (t == 0){
    float nq = norms[b*128 + h*16 + rq];
    float tp = temp[h];
    float e[16]; float mm = -1e30f;
    #pragma unroll
    for (int rk = 0; rk < 16; ++rk){
      float dot = red[0][rk]+red[1][rk]+red[2][rk]+red[3][rk];
      e[rk] = dot/(nq*norms[b*128 + 64 + h*16 + rk]) * tp;
      mm = fmaxf(mm, e[rk]);
    }
    float ssum = 0.f;
    #pragma unroll
    for (int rk = 0; rk < 16; ++rk){ e[rk] = __expf(e[rk]-mm); ssum += e[rk]; }
    float is = 1.f/ssum;
    #pragma unroll
    for (int rk = 0; rk < 16; ++rk) attn[rk] = e[rk]*is;
  }
  __syncthreads();
  float aw[16];
  #pragma unroll
  for (int rk = 0; rk < 16; ++rk) aw[rk] = attn[rk];
  const float* vb = qkv + ((size_t)b*192 + 128 + h*16)*NHW;
  float* ob = out + ((size_t)b*64 + h*16 + rq)*NHW;
  for (int n = t*4; n < NHW; n += 1024){
    float4 o; o.x = 0.f; o.y = 0.f; o.z = 0.f; o.w = 0.f;
    #pragma unroll
    for (int rk = 0; rk < 16; ++rk){
      float4 v = *(const float4*)(vb + (size_t)rk*NHW + n);
      o.x += aw[rk]*v.x; o.y += aw[rk]*v.y; o.z += aw[rk]*v.z; o.w += aw[rk]*v.w;
    }
    *(float4*)(ob + n) = o;
  }
}

// ================================================================ host
extern "C" void kernel_launch(void* const* d_in, const int* in_sizes, int n_in,
                              void* d_out, int out_size, void* d_ws, size_t ws_size,
                              hipStream_t stream){
  const float* hsi_f0     = (const float*)d_in[0];
  const float* msi_f0     = (const float*)d_in[1];
  const float* hsi_fi     = (const float*)d_in[2];
  const float* msi_fi     = (const float*)d_in[3];
  const float* sp_mlp_w   = (const float*)d_in[4];
  const float* sp_mlp_b   = (const float*)d_in[5];
  const float* spe_mlp_w  = (const float*)d_in[6];
  const float* spe_mlp_b  = (const float*)d_in[7];
  const float* spa_dw_w   = (const float*)d_in[8];
  const float* spa_dw_b   = (const float*)d_in[9];
  const float* spa_pw_w   = (const float*)d_in[10];
  const float* spa_pw_b   = (const float*)d_in[11];
  const float* spe_dw_w   = (const float*)d_in[12];
  const float* spe_dw_b   = (const float*)d_in[13];
  const float* spe_pw_w   = (const float*)d_in[14];
  const float* spe_pw_b   = (const float*)d_in[15];
  const float* sb_q_w     = (const float*)d_in[16];
  const float* sb_q_b     = (const float*)d_in[17];
  const float* sb_k_w     = (const float*)d_in[18];
  const float* sb_k_b     = (const float*)d_in[19];
  const float* sb_v_w     = (const float*)d_in[20];
  const float* sb_v_b     = (const float*)d_in[21];
  const float* sb_o_w     = (const float*)d_in[22];
  const float* sb_o_b     = (const float*)d_in[23];
  const float* sb_norm2_w = (const float*)d_in[24];
  const float* sb_ffn_in_w  = (const float*)d_in[25];
  const float* sb_ffn_dw_w  = (const float*)d_in[26];
  const float* sb_ffn_out_w = (const float*)d_in[27];
  const float* rb_norm1_w = (const float*)d_in[28];
  const float* rb_temp    = (const float*)d_in[29];
  const float* rb_qkv_w   = (const float*)d_in[30];
  const float* rb_qkv_dw_w= (const float*)d_in[31];
  const float* rb_proj_w  = (const float*)d_in[32];
  const float* rb_norm2_w = (const float*)d_in[33];
  const float* rb_ffn_in_w  = (const float*)d_in[34];
  const float* rb_ffn_dw_w  = (const float*)d_in[35];
  const float* rb_ffn_out_w = (const float*)d_in[36];

  float* W   = (float*)d_ws;
  float* Hb  = W;                 // hsi branch output      [B][64][HW]
  float* Mb  = W + (size_t)SZ;    // msi branch output; later: spectral gate G1
  float* Xb  = W + (size_t)2*SZ;  // x1
  float* Yb  = W + (size_t)3*SZ;  // y
  float* T1  = W + (size_t)4*SZ;  // dw-hsi out; QKV[0] later; rb gate out at end
  float* QKV = T1;                // 3*SZ contiguous (4SZ..7SZ) for restormer qkv
  float* TB  = W + (size_t)7*SZ;  // dw-msi out; 128-ch ffn buffer / attn out
  float* Tm  = TB;                // msi dw3 output (dead before TB reused)
  float* TB2 = W + (size_t)9*SZ;  // 3*SZ (192-ch pre-dw qkv)
  float* Pacc= W + (size_t)7*SZ;         // 4*SZ flash partial acc
  float* Pl  = W + (size_t)11*SZ;        // 131072
  float* mxb = W + (size_t)12*SZ;        // 128
  float* cmb = mxb + 256;                // 8192
  float* normb = W + (size_t)12*SZ + 9216; // 256
  // bf16 attention operand buffers in the 5SZ..7SZ region
  hbf* Qt  = (hbf*)(W + (size_t)5*SZ);            // [8][4096][16] bf16, pre-scaled 0.25*log2e
  hbf* Kt  = Qt + (size_t)8*4096*16;              // [8][4096][16]
  hbf* Vbf = Kt + (size_t)8*4096*16;              // [8][16][4096]
  float* G1 = Mb;                 // spectral gate output (Mb dead by then)

  float* outf = (float*)d_out;
  const float QS = 0.25f*LOG2E;

  // reductions
  k_max_hw<<<NB*NC, 256, 0, stream>>>(hsi_fi, mxb);
  k_chmean<<<NPIX/256, 256, 0, stream>>>(msi_fi, cmb);
  // both depthwise branches + score MLPs, one launch
  k_dw3b<<<2*SZ/256, 256, 0, stream>>>(hsi_f0, spe_dw_w, spe_dw_b, mxb, spe_mlp_w, spe_mlp_b,
                                       msi_f0, spa_dw_w, spa_dw_b, cmb, sp_mlp_w, sp_mlp_b,
                                       T1, Tm);
  // branch 1x1 convs, one launch
  k_pwbr<<<dim3(NPIX/32,1,2), 256, 0, stream>>>(T1, spe_pw_w, spe_pw_b, Hb,
                                                Tm, spa_pw_w, spa_pw_b, Mb);
  // Q,K,V projections, one launch
  k_pwqkv<<<dim3(NPIX/32,1,3), 256, 0, stream>>>(Mb, Hb, sb_q_w, sb_q_b, sb_k_w, sb_k_b,
                                                 sb_v_w, sb_v_b, Qt, Kt, Vbf, QS);
  k_mfa<<<2048, 256, 0, stream>>>(Qt, Kt, Vbf, Pacc, Pl);
  // o-proj with fused no-max flash-combine input (+msi residual)
  k_pw<<<dim3(NPIX/32,1), 256, 0, stream>>>(nullptr, sb_o_w, sb_o_b, nullptr, nullptr, nullptr, Mb, nullptr, Xb, 64, Pacc, Pl);
  // spectral ffn_in (LN fused) || restormer qkv (y=Hb+Mb in-staging, LN fused), one launch
  k_pwfi<<<dim3(NPIX/32,3,2), 256, 0, stream>>>(Xb, sb_ffn_in_w, sb_norm2_w, TB,
                                                Hb, rb_qkv_w, rb_norm1_w, Mb, Yb, TB2);
  // spectral dw-gate || restormer qkv dw3x3 (gate out -> G1=Mb, now dead)
  k_dwg2<<<SZ/256 + 3*SZ/256, 256, 0, stream>>>(TB, sb_ffn_dw_w, G1, TB2, rb_qkv_dw_w, QKV);
  // spectral ffn_out (x1 = Xb + out) || restormer rnorm, one launch
  k_pwrn<<<NPIX/32 + 256, 256, 0, stream>>>(G1, sb_ffn_out_w, Xb, Xb, QKV, normb);
  // restormer attention
  k_rattn2<<<128, 256, 0, stream>>>(QKV, normb, rb_temp, TB);
  k_pw<<<dim3(NPIX/32,1), 256, 0, stream>>>(TB, rb_proj_w, nullptr, nullptr, nullptr, nullptr, Yb, nullptr, Yb, 64, nullptr, nullptr);
  // restormer FFN + final combine: out = x1 + (y + ffn(ln(y)))
  k_pw<<<dim3(NPIX/32,2), 256, 0, stream>>>(Yb, rb_ffn_in_w, nullptr, rb_norm2_w, nullptr, nullptr, nullptr, nullptr, TB, 128, nullptr, nullptr);
  k_dwgate<<<SZ/256, 256, 0, stream>>>(TB, rb_ffn_dw_w, T1);
  k_pw<<<dim3(NPIX/32,1), 256, 0, stream>>>(T1, rb_ffn_out_w, nullptr, nullptr, nullptr, nullptr, Xb, Yb, outf, 64, nullptr, nullptr);
}

// Round 23
// 232.285 us; speedup vs baseline: 1.0415x; 1.0415x over previous
//
#include <hip/hip_runtime.h>
#include <hip/hip_bf16.h>

#define NB 2
#define NC 64
#define NHW 4096
#define NPIX (NB*NHW)          // 8192
#define SZ   (NB*NC*NHW)       // 524288 floats per 64-ch fp32 tensor
#define LOG2E 1.4426950408889634f

typedef __attribute__((ext_vector_type(8))) short bf16x8;
typedef __attribute__((ext_vector_type(4))) float f32x4;
typedef __hip_bfloat16 hbf;

__device__ __forceinline__ float clamp01(float v){ return fminf(fmaxf(v, 0.f), 1.f); }
__device__ __forceinline__ float fexp2(float x){ return __builtin_amdgcn_exp2f(x); }  // raw v_exp_f32

// ---------------------------------------------------------------- reductions
__global__ __launch_bounds__(256) void k_max_hw(const float* __restrict__ in, float* __restrict__ mx){
  int bc = blockIdx.x; int t = threadIdx.x;
  const float* p = in + (size_t)bc*NHW;
  float m = -1e30f;
  for (int n = t; n < NHW; n += 256) m = fmaxf(m, p[n]);
  #pragma unroll
  for (int off = 32; off; off >>= 1) m = fmaxf(m, __shfl_xor(m, off));
  __shared__ float sm[4];
  if ((t & 63) == 0) sm[t >> 6] = m;
  __syncthreads();
  if (t == 0) mx[bc] = fmaxf(fmaxf(sm[0], sm[1]), fmaxf(sm[2], sm[3]));
}

__global__ __launch_bounds__(256) void k_chmean(const float* __restrict__ in, float* __restrict__ out){
  int p = blockIdx.x*256 + threadIdx.x;         // 0..8191
  int b = p >> 12, n = p & 4095;
  const float* base = in + (size_t)b*NC*NHW + n;
  float s = 0.f;
  #pragma unroll
  for (int c = 0; c < 64; ++c) s += base[c*NHW];
  out[p] = s * (1.0f/64.0f);
}

// ---------------------------------------------------------------- both depthwise 3x3 branches + score MLPs, one launch
__global__ __launch_bounds__(256) void k_dw3b(const float* __restrict__ hsi0, const float* __restrict__ wh,
    const float* __restrict__ bh, const float* __restrict__ mxb,
    const float* __restrict__ spe_w, const float* __restrict__ spe_b,
    const float* __restrict__ msi0, const float* __restrict__ wm, const float* __restrict__ bm,
    const float* __restrict__ cmb, const float* __restrict__ spw, const float* __restrict__ spb,
    float* __restrict__ out0, float* __restrict__ out1){
  int bb = blockIdx.x;                    // 0..4095
  int br = bb >= (SZ/256);                // scalar branch
  int bbl = br ? bb - SZ/256 : bb;        // 0..2047
  int b = bbl >> 10;                      // scalar
  int c = (bbl >> 4) & 63;                // scalar
  int t = threadIdx.x;
  int pix = (bbl & 15)*256 + t;
  const float* in = br ? msi0 : hsi0;
  const float* w  = br ? wm : wh;
  const float* bs = br ? bm : bh;
  float* out      = br ? out1 : out0;
  int y = pix >> 6, x = pix & 63;
  const float* base = in + (size_t)(b*64 + c)*NHW;
  float wf[9];
  #pragma unroll
  for (int i = 0; i < 9; ++i) wf[i] = w[c*9 + i];
  float acc = 0.f;
  #pragma unroll
  for (int ky = -1; ky <= 1; ++ky){
    int yy = y + ky; if ((unsigned)yy >= 64u) continue;
    #pragma unroll
    for (int kx = -1; kx <= 1; ++kx){
      int xx = x + kx; if ((unsigned)xx >= 64u) continue;
      acc += base[yy*64 + xx] * wf[(ky+1)*3 + (kx+1)];
    }
  }
  acc += bs[c];
  if (!br){
    float spe = spe_b[c];
    #pragma unroll 8
    for (int i = 0; i < 64; ++i) spe += spe_w[c*64 + i] * mxb[b*64 + i];
    acc += clamp01(spe);
  } else {
    float z = spw[c] * cmb[b*4096 + pix] + spb[c];
    acc += clamp01(z);
  }
  out[(size_t)(b*64 + c)*NHW + pix] = acc;
}

// ---------------------------------------------------------------- lean simple pw body (64->64, flat args)
__device__ __forceinline__ void pw_simple(const float* __restrict__ in, const float* __restrict__ w,
    const float* __restrict__ bias, float* __restrict__ outf,
    hbf* __restrict__ tq, float tscale, hbf* __restrict__ cq, int ptile){
  __shared__ __align__(16) float Xs[64][32];
  __shared__ __align__(16) float Wt[64][64];    // [i][o]
  int t = threadIdx.x;
  int b = ptile >> 7; int n0 = (ptile & 127)*32;
  const float* inb = in + (size_t)b*64*NHW + n0;
  #pragma unroll
  for (int k = 0; k < 8; ++k){
    int i = k*8 + (t >> 5); int n = t & 31;
    Xs[i][n] = inb[(size_t)i*NHW + n];
  }
  #pragma unroll
  for (int k = 0; k < 16; ++k){
    int idx = k*256 + t; int o = idx & 63, i = idx >> 6;
    Wt[i][o] = w[(size_t)o*64 + i];
  }
  __syncthreads();
  int tn = t & 15, to = t >> 4;
  float a0x=0,a0y=0,a1x=0,a1y=0,a2x=0,a2y=0,a3x=0,a3y=0;
  #pragma unroll
  for (int i = 0; i < 64; ++i){
    const float2 xv = *(const float2*)&Xs[i][tn*2];
    const float4 wv = *(const float4*)&Wt[i][to*4];
    a0x += wv.x*xv.x; a0y += wv.x*xv.y;
    a1x += wv.y*xv.x; a1y += wv.y*xv.y;
    a2x += wv.z*xv.x; a2y += wv.z*xv.y;
    a3x += wv.w*xv.x; a3y += wv.w*xv.y;
  }
  float ax[4] = {a0x,a1x,a2x,a3x}, ay[4] = {a0y,a1y,a2y,a3y};
  #pragma unroll
  for (int oo = 0; oo < 4; ++oo){
    int o = to*4 + oo;
    float bv = bias[o];
    size_t obase = ((size_t)b*64 + o)*NHW + n0 + tn*2;
    float v0 = ax[oo] + bv, v1 = ay[oo] + bv;
    if (tq){
      int h = o >> 4, d = o & 15;
      size_t tb = ((size_t)(b*4 + h)*4096 + n0 + tn*2)*16 + d;
      tq[tb]    = __float2bfloat16(v0*tscale);
      tq[tb+16] = __float2bfloat16(v1*tscale);
    }
    if (cq){
      cq[obase+0] = __float2bfloat16(v0);
      cq[obase+1] = __float2bfloat16(v1);
    }
    if (outf){
      float2 vv; vv.x = v0; vv.y = v1;
      *(float2*)(outf + obase) = vv;
    }
  }
}

// two branch 1x1 convs in one launch: grid (256,1,2), flat args, scalar z-select
__global__ __launch_bounds__(256) void k_pwbr(const float* __restrict__ t1, const float* __restrict__ w0,
    const float* __restrict__ b0, float* __restrict__ hb,
    const float* __restrict__ tm, const float* __restrict__ w1,
    const float* __restrict__ b1, float* __restrict__ mb){
  int z = blockIdx.z;
  const float* in = z ? tm : t1;
  const float* w  = z ? w1 : w0;
  const float* bs = z ? b1 : b0;
  float* out      = z ? mb : hb;
  pw_simple(in, w, bs, out, nullptr, 1.f, nullptr, blockIdx.x);
}

// Q,K,V projections in one launch: grid (256,1,3), flat args, scalar z-select
__global__ __launch_bounds__(256) void k_pwqkv(const float* __restrict__ mb, const float* __restrict__ hb,
    const float* __restrict__ qw, const float* __restrict__ qb,
    const float* __restrict__ kw, const float* __restrict__ kb,
    const float* __restrict__ vw, const float* __restrict__ vb,
    hbf* __restrict__ qt, hbf* __restrict__ kt, hbf* __restrict__ vbf, float qs){
  int z = blockIdx.z;
  const float* in = (z == 0) ? mb : hb;
  const float* w  = (z == 0) ? qw : ((z == 1) ? kw : vw);
  const float* bs = (z == 0) ? qb : ((z == 1) ? kb : vb);
  hbf* tq = (z == 0) ? qt : ((z == 1) ? kt : nullptr);
  float ts = (z == 0) ? qs : 1.f;
  hbf* cq = (z == 2) ? vbf : nullptr;
  pw_simple(in, w, bs, nullptr, tq, ts, cq, blockIdx.x);
}

// ---------------------------------------------------------------- full-featured pw body (flat args)
// no-max flash combine: v = (sum_c Pacc_c) / (sum_c Pl_c)
__device__ __forceinline__ void pw_full(const float* __restrict__ in, const float* __restrict__ w,
    const float* __restrict__ bias, const float* __restrict__ lnw,
    const float* __restrict__ in2, float* __restrict__ add_out,
    const float* __restrict__ r1, const float* __restrict__ r2,
    float* __restrict__ outf, int OC,
    const float* __restrict__ Pacc, const float* __restrict__ Pl,
    int ptile, int oc0){
  __shared__ __align__(16) float Xs[64][32];
  __shared__ __align__(16) float Wt[64][64];    // [i][o]
  __shared__ float psum[8][32], psqs[8][32];
  __shared__ float invs[32];
  __shared__ float fs[4][32];                   // [h][n] 1/L
  int t = threadIdx.x;
  int b = ptile >> 7; int n0 = (ptile & 127)*32;
  const float* inb = in ? in + (size_t)b*64*NHW + n0 : nullptr;
  const float* inb2 = in2 ? in2 + (size_t)b*64*NHW + n0 : nullptr;
  float* aob = add_out ? add_out + (size_t)b*64*NHW + n0 : nullptr;
  if (Pacc){
    if (t < 128){
      int h = t >> 5, n = t & 31;
      int bh = b*4 + h, q = n0 + n;
      float L = Pl[(size_t)bh*4096 + q] + Pl[(size_t)(8+bh)*4096 + q]
              + Pl[(size_t)(16+bh)*4096 + q] + Pl[(size_t)(24+bh)*4096 + q];
      fs[h][n] = 1.0f / L;
    }
    __syncthreads();
  }
  float ps = 0.f, pss = 0.f;
  #pragma unroll
  for (int k = 0; k < 8; ++k){
    int i = k*8 + (t >> 5); int n = t & 31;
    float v;
    if (Pacc){
      int h = i >> 4, d = i & 15, bh = b*4 + h;
      const float* pb = Pacc + ((size_t)(bh*16 + d))*4096 + n0 + n;
      v = (pb[0] + pb[(size_t)SZ] + pb[(size_t)2*SZ] + pb[(size_t)3*SZ]) * fs[h][n];
    } else {
      v = inb[(size_t)i*NHW + n];
      if (inb2) v += inb2[(size_t)i*NHW + n];
    }
    Xs[i][n] = v;
    if (aob && oc0 == 0) aob[(size_t)i*NHW + n] = v;
    ps += v; pss += v*v;
  }
  if (lnw){ psum[t>>5][t&31] = ps; psqs[t>>5][t&31] = pss; }
  #pragma unroll
  for (int k = 0; k < 16; ++k){
    int idx = k*256 + t; int o = idx & 63, i = idx >> 6;
    float wv = w[(size_t)(oc0 + o)*64 + i];
    if (lnw) wv *= lnw[i];
    Wt[i][o] = wv;
  }
  __syncthreads();
  if (lnw){
    if (t < 32){
      float s1 = 0.f, s2 = 0.f;
      #pragma unroll
      for (int g = 0; g < 8; ++g){ s1 += psum[g][t]; s2 += psqs[g][t]; }
      float mu = s1*(1.0f/64.0f);
      float var = s2*(1.0f/64.0f) - mu*mu;
      invs[t] = rsqrtf(fmaxf(var, 0.f) + 1e-5f);
    }
    __syncthreads();
  }
  int tn = t & 15, to = t >> 4;
  float a0x=0,a0y=0,a1x=0,a1y=0,a2x=0,a2y=0,a3x=0,a3y=0;
  #pragma unroll
  for (int i = 0; i < 64; ++i){
    const float2 xv = *(const float2*)&Xs[i][tn*2];
    const float4 wv = *(const float4*)&Wt[i][to*4];
    a0x += wv.x*xv.x; a0y += wv.x*xv.y;
    a1x += wv.y*xv.x; a1y += wv.y*xv.y;
    a2x += wv.z*xv.x; a2y += wv.z*xv.y;
    a3x += wv.w*xv.x; a3y += wv.w*xv.y;
  }
  float sx = 1.f, sy = 1.f;
  if (lnw){ sx = invs[tn*2+0]; sy = invs[tn*2+1]; }
  float ax[4] = {a0x,a1x,a2x,a3x}, ay[4] = {a0y,a1y,a2y,a3y};
  #pragma unroll
  for (int oo = 0; oo < 4; ++oo){
    int o = oc0 + to*4 + oo;
    float bv = bias ? bias[o] : 0.f;
    size_t obase = ((size_t)b*OC + o)*NHW + n0 + tn*2;
    float v0 = ax[oo]*sx + bv, v1 = ay[oo]*sy + bv;
    if (r1){ v0 += r1[obase+0]; v1 += r1[obase+1]; }
    if (r2){ v0 += r2[obase+0]; v1 += r2[obase+1]; }
    if (outf){
      float2 vv; vv.x = v0; vv.y = v1;
      *(float2*)(outf + obase) = vv;
    }
  }
}

__global__ __launch_bounds__(256) void k_pw(const float* __restrict__ in, const float* __restrict__ w,
    const float* __restrict__ bias, const float* __restrict__ lnw,
    const float* __restrict__ in2, float* __restrict__ add_out,
    const float* __restrict__ r1, const float* __restrict__ r2,
    float* __restrict__ outf, int OC,
    const float* __restrict__ Pacc, const float* __restrict__ Pl){
  pw_full(in, w, bias, lnw, in2, add_out, r1, r2, outf, OC, Pacc, Pl, blockIdx.x, blockIdx.y*64);
}

// spectral ffn_in (z=0, OC=128) || restormer qkv (z=1, OC=192): grid (256,3,2)
__global__ __launch_bounds__(256) void k_pwfi(const float* __restrict__ xb, const float* __restrict__ w0,
    const float* __restrict__ ln0, float* __restrict__ tb,
    const float* __restrict__ hb, const float* __restrict__ w1, const float* __restrict__ ln1,
    const float* __restrict__ mb, float* __restrict__ yb, float* __restrict__ tb2){
  int z = blockIdx.z;
  int OC = z ? 192 : 128;
  int oc0 = blockIdx.y*64;
  if (oc0 >= OC) return;
  const float* in  = z ? hb : xb;
  const float* w   = z ? w1 : w0;
  const float* lnw = z ? ln1 : ln0;
  const float* in2 = z ? mb : nullptr;
  float* aout      = z ? yb : nullptr;
  float* outf      = z ? tb2 : tb;
  pw_full(in, w, nullptr, lnw, in2, aout, nullptr, nullptr, outf, OC, nullptr, nullptr, blockIdx.x, oc0);
}

// spectral ffn_out (blocks 0..255) || restormer rnorm (blocks 256..511)
__global__ __launch_bounds__(256) void k_pwrn(const float* __restrict__ g1, const float* __restrict__ w,
    const float* __restrict__ xb, float* __restrict__ xout,
    const float* __restrict__ qkv, float* __restrict__ norms){
  int bb = blockIdx.x;
  if (bb < NPIX/32){
    pw_full(g1, w, nullptr, nullptr, nullptr, nullptr, xb, nullptr, xout, 64, nullptr, nullptr, bb, 0);
  } else {
    int blk = bb - NPIX/32; int b = blk >> 7, r = blk & 127;
    int t = threadIdx.x;
    const float* p = qkv + ((size_t)b*192 + r)*NHW;
    float ss = 0.f;
    for (int i = t*4; i < NHW; i += 1024){
      float4 v = *(const float4*)(p + i);
      ss += v.x*v.x + v.y*v.y + v.z*v.z + v.w*v.w;
    }
    #pragma unroll
    for (int off = 32; off; off >>= 1) ss += __shfl_xor(ss, off);
    __shared__ float sm[4];
    if ((t & 63) == 0) sm[t >> 6] = ss;
    __syncthreads();
    if (t == 0) norms[blk] = fmaxf(sqrtf(sm[0]+sm[1]+sm[2]+sm[3]), 1e-12f);
  }
}

// ---------------------------------------------------------------- MFMA flash cross-attention, hd=16, n=4096
// grid 2048 = qt(64) x bh(8) x chunk(4); block 256 = 4 waves; wave = 16 queries.
// No-max softmax: Qt pre-scaled by 0.25*log2e, P = exp2(score) unnormalized
// (scores bounded; fp32 has 2^127 headroom). Combine: O = sum Pacc / sum Pl.
// [r21-proven form: single acc, 3 loads in flight, VGPR 24, occ ~75%]
__global__ __launch_bounds__(256) void k_mfa(const hbf* __restrict__ Qt, const hbf* __restrict__ Kt,
                                             const hbf* __restrict__ Vb, float* __restrict__ Pacc,
                                             float* __restrict__ Pl){
  int blk = blockIdx.x;
  int qt = blk & 63; int bh = (blk >> 6) & 7; int c = blk >> 9;   // c 0..3
  int t = threadIdx.x;
  int w = t >> 6, l = t & 63;
  int lg = l >> 4, lq = l & 15;
  int q0 = qt*64 + w*16;
  int rho = ((lq >> 2) << 3) + (lq & 3);        // 0-3,8-11,16-19,24-27
  bf16x8 qf = {};
  if (lg < 2) qf = *(const bf16x8*)&Qt[((size_t)bh*4096 + q0 + lq)*16 + lg*8];
  f32x4 acc = {0.f, 0.f, 0.f, 0.f};
  float lsum = 0.f;
  const hbf* Ktb = Kt + ((size_t)bh*4096 + c*1024)*16;
  const hbf* Vbb = Vb + (size_t)bh*16*4096 + c*1024;
  for (int kb = 0; kb < 1024; kb += 32){
    bf16x8 kf0 = {}, kf1 = {};
    if (lg < 2){
      kf0 = *(const bf16x8*)&Ktb[(size_t)(kb + rho)*16 + lg*8];
      kf1 = *(const bf16x8*)&Ktb[(size_t)(kb + rho + 4)*16 + lg*8];
    }
    f32x4 z = {0.f, 0.f, 0.f, 0.f};
    f32x4 s0 = __builtin_amdgcn_mfma_f32_16x16x32_bf16(kf0, qf, z, 0, 0, 0);
    f32x4 s1 = __builtin_amdgcn_mfma_f32_16x16x32_bf16(kf1, qf, z, 0, 0, 0);
    float p[8];
    p[0]=s0[0]; p[1]=s0[1]; p[2]=s0[2]; p[3]=s0[3];   // keys lg*8+0..3
    p[4]=s1[0]; p[5]=s1[1]; p[6]=s1[2]; p[7]=s1[3];   // keys lg*8+4..7
    #pragma unroll
    for (int i = 0; i < 8; ++i){ p[i] = fexp2(p[i]); lsum += p[i]; }
    bf16x8 pf;
    #pragma unroll
    for (int j = 0; j < 8; ++j){
      hbf hb = __float2bfloat16(p[j]);
      pf[j] = *reinterpret_cast<short*>(&hb);
    }
    bf16x8 vf = *(const bf16x8*)&Vbb[(size_t)lq*4096 + kb + lg*8];
    acc = __builtin_amdgcn_mfma_f32_16x16x32_bf16(vf, pf, acc, 0, 0, 0);
  }
  // reduce per-lane lsum across the 4 lane groups (same query lq)
  lsum += __shfl_xor(lsum, 16);
  lsum += __shfl_xor(lsum, 32);
  int pb = c*8 + bh;
  if (lg == 0) Pl[(size_t)pb*4096 + q0 + lq] = lsum;
  #pragma unroll
  for (int r = 0; r < 4; ++r){
    int d = lg*4 + r;
    Pacc[((size_t)pb*16 + d)*4096 + q0 + lq] = acc[r];
  }
}

// ---------------------------------------------------------------- FFN dw3x3 + chunk + gelu gate (128->64)
__device__ __forceinline__ void dwgate_body(const float* __restrict__ in, const float* __restrict__ w,
                                            float* __restrict__ out, int g){
  int pix = g & 4095; int c = (g >> 12) & 63; int b = g >> 18;
  int y = pix >> 6, x = pix & 63;
  const float* p1 = in + ((size_t)b*128 + c)*NHW;
  const float* p2 = in + ((size_t)b*128 + 64 + c)*NHW;
  float w1[9], w2[9];
  #pragma unroll
  for (int i = 0; i < 9; ++i){ w1[i] = w[c*9+i]; w2[i] = w[(64+c)*9+i]; }
  float a = 0.f, bb = 0.f;
  #pragma unroll
  for (int ky = -1; ky <= 1; ++ky){
    int yy = y + ky; if ((unsigned)yy >= 64u) continue;
    #pragma unroll
    for (int kx = -1; kx <= 1; ++kx){
      int xx = x + kx; if ((unsigned)xx >= 64u) continue;
      int off = yy*64 + xx; int wi = (ky+1)*3 + (kx+1);
      a  += p1[off]*w1[wi];
      bb += p2[off]*w2[wi];
    }
  }
  float gl = 0.5f*a*(1.0f + erff(a*0.70710678118654752f));   // exact gelu
  out[g] = gl*bb;
}

__global__ __launch_bounds__(256) void k_dwgate(const float* __restrict__ in, const float* __restrict__ w,
                                                float* __restrict__ out){
  dwgate_body(in, w, out, blockIdx.x*256 + threadIdx.x);
}

// dwgate (spectral) || dw192 (restormer qkv) in one launch, scalar block split
__global__ __launch_bounds__(256) void k_dwg2(const float* __restrict__ inG, const float* __restrict__ wG,
                                              float* __restrict__ outG,
                                              const float* __restrict__ inD, const float* __restrict__ wD,
                                              float* __restrict__ outD){
  int bb = blockIdx.x;
  if (bb < SZ/256){
    dwgate_body(inG, wG, outG, bb*256 + threadIdx.x);
  } else {
    int g = (bb - SZ/256)*256 + threadIdx.x;    // B*192*4096
    int pix = g & 4095; int bc = g >> 12; int c = bc % 192;
    int y = pix >> 6, x = pix & 63;
    const float* p = inD + (size_t)bc*NHW;
    float wf[9];
    #pragma unroll
    for (int i = 0; i < 9; ++i) wf[i] = wD[c*9+i];
    float acc = 0.f;
    #pragma unroll
    for (int ky = -1; ky <= 1; ++ky){
      int yy = y + ky; if ((unsigned)yy >= 64u) continue;
      #pragma unroll
      for (int kx = -1; kx <= 1; ++kx){
        int xx = x + kx; if ((unsigned)xx >= 64u) continue;
        acc += p[yy*64 + xx]*wf[(ky+1)*3 + (kx+1)];
      }
    }
    outD[g] = acc;
  }
}

// ---------------------------------------------------------------- restormer channel attention
__global__ __launch_bounds__(256) void k_rattn2(const float* __restrict__ qkv, const float* __restrict__ norms,
                                                const float* __restrict__ temp, float* __restrict__ out){
  int blk = blockIdx.x; int rq = blk & 15, h = (blk >> 4) & 3, b = blk >> 6;
  int t = threadIdx.x;
  const float* bq = qkv + ((size_t)b*192 + h*16 + rq)*NHW;
  const float* bk = qkv + ((size_t)b*192 + 64 + h*16)*NHW;
  float p[16];
  #pragma unroll
  for (int rk = 0; rk < 16; ++rk) p[rk] = 0.f;
  for (int n = t*4; n < NHW; n += 1024){
    float4 qv4 = *(const float4*)(bq + n);
    #pragma unroll
    for (int rk = 0; rk < 16; ++rk){
      float4 kv = *(const float4*)(bk + (size_t)rk*NHW + n);
      p[rk] += qv4.x*kv.x + qv4.y*kv.y + qv4.z*kv.z + qv4.w*kv.w;
    }
  }
  #pragma unroll
  for (int rk = 0; rk < 16; ++rk)
    #pragma unroll
    for (int off = 32; off; off >>= 1) p[rk] += __shfl_xor(p[rk], off);
  __shared__ float red[4][16];
  if ((t & 63) == 0){
    int wv_ = t >> 6;
    #pragma unroll
    for (int rk = 0; rk < 16; ++rk) red[wv_][rk] = p[rk];
  }
  __syncthreads();
  __shared__ float attn[16];
  if (t == 0){
    float nq = norms[b*128 + h*16 + rq];
    float tp = temp[h];
    float e[16]; float mm = -1e30f;
    #pragma unroll
    for (int rk = 0; rk < 16; ++rk){
      float dot = red[0][rk]+red[1][rk]+red[2][rk]+red[3][rk];
      e[rk] = dot/(nq*norms[b*128 + 64 + h*16 + rk]) * tp;
      mm = fmaxf(mm, e[rk]);
    }
    float ssum = 0.f;
    #pragma unroll
    for (int rk = 0; rk < 16; ++rk){ e[rk] = __expf(e[rk]-mm); ssum += e[rk]; }
    float is = 1.f/ssum;
    #pragma unroll
    for (int rk = 0; rk < 16; ++rk) attn[rk] = e[rk]*is;
  }
  __syncthreads();
  float aw[16];
  #pragma unroll
  for (int rk = 0; rk < 16; ++rk) aw[rk] = attn[rk];
  const float* vb = qkv + ((size_t)b*192 + 128 + h*16)*NHW;
  float* ob = out + ((size_t)b*64 + h*16 + rq)*NHW;
  for (int n = t*4; n < NHW; n += 1024){
    float4 o; o.x = 0.f; o.y = 0.f; o.z = 0.f; o.w = 0.f;
    #pragma unroll
    for (int rk = 0; rk < 16; ++rk){
      float4 v = *(const float4*)(vb + (size_t)rk*NHW + n);
      o.x += aw[rk]*v.x; o.y += aw[rk]*v.y; o.z += aw[rk]*v.z; o.w += aw[rk]*v.w;
    }
    *(float4*)(ob + n) = o;
  }
}

// ================================================================ host
extern "C" void kernel_launch(void* const* d_in, const int* in_sizes, int n_in,
                              void* d_out, int out_size, void* d_ws, size_t ws_size,
                              hipStream_t stream){
  const float* hsi_f0     = (const float*)d_in[0];
  const float* msi_f0     = (const float*)d_in[1];
  const float* hsi_fi     = (const float*)d_in[2];
  const float* msi_fi     = (const float*)d_in[3];
  const float* sp_mlp_w   = (const float*)d_in[4];
  const float* sp_mlp_b   = (const float*)d_in[5];
  const float* spe_mlp_w  = (const float*)d_in[6];
  const float* spe_mlp_b  = (const float*)d_in[7];
  const float* spa_dw_w   = (const float*)d_in[8];
  const float* spa_dw_b   = (const float*)d_in[9];
  const float* spa_pw_w   = (const float*)d_in[10];
  const float* spa_pw_b   = (const float*)d_in[11];
  const float* spe_dw_w   = (const float*)d_in[12];
  const float* spe_dw_b   = (const float*)d_in[13];
  const float* spe_pw_w   = (const float*)d_in[14];
  const float* spe_pw_b   = (const float*)d_in[15];
  const float* sb_q_w     = (const float*)d_in[16];
  const float* sb_q_b     = (const float*)d_in[17];
  const float* sb_k_w     = (const float*)d_in[18];
  const float* sb_k_b     = (const float*)d_in[19];
  const float* sb_v_w     = (const float*)d_in[20];
  const float* sb_v_b     = (const float*)d_in[21];
  const float* sb_o_w     = (const float*)d_in[22];
  const float* sb_o_b     = (const float*)d_in[23];
  const float* sb_norm2_w = (const float*)d_in[24];
  const float* sb_ffn_in_w  = (const float*)d_in[25];
  const float* sb_ffn_dw_w  = (const float*)d_in[26];
  const float* sb_ffn_out_w = (const float*)d_in[27];
  const float* rb_norm1_w = (const float*)d_in[28];
  const float* rb_temp    = (const float*)d_in[29];
  const float* rb_qkv_w   = (const float*)d_in[30];
  const float* rb_qkv_dw_w= (const float*)d_in[31];
  const float* rb_proj_w  = (const float*)d_in[32];
  const float* rb_norm2_w = (const float*)d_in[33];
  const float* rb_ffn_in_w  = (const float*)d_in[34];
  const float* rb_ffn_dw_w  = (const float*)d_in[35];
  const float* rb_ffn_out_w = (const float*)d_in[36];

  float* W   = (float*)d_ws;
  float* Hb  = W;                 // hsi branch output      [B][64][HW]
  float* Mb  = W + (size_t)SZ;    // msi branch output; later: spectral gate G1
  float* Xb  = W + (size_t)2*SZ;  // x1
  float* Yb  = W + (size_t)3*SZ;  // y
  float* T1  = W + (size_t)4*SZ;  // dw-hsi out; QKV[0] later; rb gate out at end
  float* QKV = T1;                // 3*SZ contiguous (4SZ..7SZ) for restormer qkv
  float* TB  = W + (size_t)7*SZ;  // dw-msi out; 128-ch ffn buffer / attn out
  float* Tm  = TB;                // msi dw3 output (dead before TB reused)
  float* TB2 = W + (size_t)9*SZ;  // 3*SZ (192-ch pre-dw qkv)
  float* Pacc= W + (size_t)7*SZ;         // 4*SZ flash partial acc
  float* Pl  = W + (size_t)11*SZ;        // 131072
  float* mxb = W + (size_t)12*SZ;        // 128
  float* cmb = mxb + 256;                // 8192
  float* normb = W + (size_t)12*SZ + 9216; // 256
  // bf16 attention operand buffers in the 5SZ..7SZ region
  hbf* Qt  = (hbf*)(W + (size_t)5*SZ);            // [8][4096][16] bf16, pre-scaled 0.25*log2e
  hbf* Kt  = Qt + (size_t)8*4096*16;              // [8][4096][16]
  hbf* Vbf = Kt + (size_t)8*4096*16;              // [8][16][4096]
  float* G1 = Mb;                 // spectral gate output (Mb dead by then)

  float* outf = (float*)d_out;
  const float QS = 0.25f*LOG2E;

  // reductions
  k_max_hw<<<NB*NC, 256, 0, stream>>>(hsi_fi, mxb);
  k_chmean<<<NPIX/256, 256, 0, stream>>>(msi_fi, cmb);
  // both depthwise branches + score MLPs, one launch
  k_dw3b<<<2*SZ/256, 256, 0, stream>>>(hsi_f0, spe_dw_w, spe_dw_b, mxb, spe_mlp_w, spe_mlp_b,
                                       msi_f0, spa_dw_w, spa_dw_b, cmb, sp_mlp_w, sp_mlp_b,
                                       T1, Tm);
  // branch 1x1 convs, one launch
  k_pwbr<<<dim3(NPIX/32,1,2), 256, 0, stream>>>(T1, spe_pw_w, spe_pw_b, Hb,
                                                Tm, spa_pw_w, spa_pw_b, Mb);
  // Q,K,V projections, one launch
  k_pwqkv<<<dim3(NPIX/32,1,3), 256, 0, stream>>>(Mb, Hb, sb_q_w, sb_q_b, sb_k_w, sb_k_b,
                                                 sb_v_w, sb_v_b, Qt, Kt, Vbf, QS);
  k_mfa<<<2048, 256, 0, stream>>>(Qt, Kt, Vbf, Pacc, Pl);
  // o-proj with fused no-max flash-combine input (+msi residual)
  k_pw<<<dim3(NPIX/32,1), 256, 0, stream>>>(nullptr, sb_o_w, sb_o_b, nullptr, nullptr, nullptr, Mb, nullptr, Xb, 64, Pacc, Pl);
  // spectral ffn_in (LN fused) || restormer qkv (y=Hb+Mb in-staging, LN fused), one launch
  k_pwfi<<<dim3(NPIX/32,3,2), 256, 0, stream>>>(Xb, sb_ffn_in_w, sb_norm2_w, TB,
                                                Hb, rb_qkv_w, rb_norm1_w, Mb, Yb, TB2);
  // spectral dw-gate || restormer qkv dw3x3 (gate out -> G1=Mb, now dead)
  k_dwg2<<<SZ/256 + 3*SZ/256, 256, 0, stream>>>(TB, sb_ffn_dw_w, G1, TB2, rb_qkv_dw_w, QKV);
  // spectral ffn_out (x1 = Xb + out) || restormer rnorm, one launch
  k_pwrn<<<NPIX/32 + 256, 256, 0, stream>>>(G1, sb_ffn_out_w, Xb, Xb, QKV, normb);
  // restormer attention
  k_rattn2<<<128, 256, 0, stream>>>(QKV, normb, rb_temp, TB);
  k_pw<<<dim3(NPIX/32,1), 256, 0, stream>>>(TB, rb_proj_w, nullptr, nullptr, nullptr, nullptr, Yb, nullptr, Yb, 64, nullptr, nullptr);
  // restormer FFN + final combine: out = x1 + (y + ffn(ln(y)))
  k_pw<<<dim3(NPIX/32,2), 256, 0, stream>>>(Yb, rb_ffn_in_w, nullptr, rb_norm2_w, nullptr, nullptr, nullptr, nullptr, TB, 128, nullptr, nullptr);
  k_dwgate<<<SZ/256, 256, 0, stream>>>(TB, rb_ffn_dw_w, T1);
  k_pw<<<dim3(NPIX/32,1), 256, 0, stream>>>(T1, rb_ffn_out_w, nullptr, nullptr, nullptr, nullptr, Xb, Yb, outf, 64, nullptr, nullptr);
}

// Round 24
// 227.091 us; speedup vs baseline: 1.0654x; 1.0229x over previous
//
#include <hip/hip_runtime.h>
#include <hip/hip_bf16.h>

#define NB 2
#define NC 64
#define NHW 4096
#define NPIX (NB*NHW)          // 8192
#define SZ   (NB*NC*NHW)       // 524288 floats per 64-ch fp32 tensor
#define LOG2E 1.4426950408889634f

typedef __attribute__((ext_vector_type(8))) short bf16x8;
typedef __attribute__((ext_vector_type(4))) float f32x4;
typedef __hip_bfloat16 hbf;

__device__ __forceinline__ float clamp01(float v){ return fminf(fmaxf(v, 0.f), 1.f); }
__device__ __forceinline__ float fexp2(float x){ return __builtin_amdgcn_exp2f(x); }  // raw v_exp_f32

// ---------------------------------------------------------------- fused reductions: max-over-HW (blocks 0..127) || channel-mean (blocks 128..159)
// pwrn-proven pattern: scalar blockIdx split, BOTH branches contain a barrier.
__global__ __launch_bounds__(256) void k_maxmean(const float* __restrict__ hsi_fi, float* __restrict__ mx,
                                                 const float* __restrict__ msi_fi, float* __restrict__ cm){
  int bb = blockIdx.x; int t = threadIdx.x;
  __shared__ float sm[4];
  if (bb < NB*NC){
    const float* p = hsi_fi + (size_t)bb*NHW;
    float m = -1e30f;
    for (int n = t; n < NHW; n += 256) m = fmaxf(m, p[n]);
    #pragma unroll
    for (int off = 32; off; off >>= 1) m = fmaxf(m, __shfl_xor(m, off));
    if ((t & 63) == 0) sm[t >> 6] = m;
    __syncthreads();
    if (t == 0) mx[bb] = fmaxf(fmaxf(sm[0], sm[1]), fmaxf(sm[2], sm[3]));
  } else {
    int p = (bb - NB*NC)*256 + t;               // 0..8191
    int b = p >> 12, n = p & 4095;
    const float* base = msi_fi + (size_t)b*NC*NHW + n;
    float s = 0.f;
    #pragma unroll
    for (int c = 0; c < 64; ++c) s += base[c*NHW];
    __syncthreads();                            // barrier parity with max branch
    cm[p] = s * (1.0f/64.0f);
  }
}

// ---------------------------------------------------------------- both depthwise 3x3 branches + score MLPs, one launch
__global__ __launch_bounds__(256) void k_dw3b(const float* __restrict__ hsi0, const float* __restrict__ wh,
    const float* __restrict__ bh, const float* __restrict__ mxb,
    const float* __restrict__ spe_w, const float* __restrict__ spe_b,
    const float* __restrict__ msi0, const float* __restrict__ wm, const float* __restrict__ bm,
    const float* __restrict__ cmb, const float* __restrict__ spw, const float* __restrict__ spb,
    float* __restrict__ out0, float* __restrict__ out1){
  int bb = blockIdx.x;                    // 0..4095
  int br = bb >= (SZ/256);                // scalar branch
  int bbl = br ? bb - SZ/256 : bb;        // 0..2047
  int b = bbl >> 10;                      // scalar
  int c = (bbl >> 4) & 63;                // scalar
  int t = threadIdx.x;
  int pix = (bbl & 15)*256 + t;
  const float* in = br ? msi0 : hsi0;
  const float* w  = br ? wm : wh;
  const float* bs = br ? bm : bh;
  float* out      = br ? out1 : out0;
  int y = pix >> 6, x = pix & 63;
  const float* base = in + (size_t)(b*64 + c)*NHW;
  float wf[9];
  #pragma unroll
  for (int i = 0; i < 9; ++i) wf[i] = w[c*9 + i];
  float acc = 0.f;
  #pragma unroll
  for (int ky = -1; ky <= 1; ++ky){
    int yy = y + ky; if ((unsigned)yy >= 64u) continue;
    #pragma unroll
    for (int kx = -1; kx <= 1; ++kx){
      int xx = x + kx; if ((unsigned)xx >= 64u) continue;
      acc += base[yy*64 + xx] * wf[(ky+1)*3 + (kx+1)];
    }
  }
  acc += bs[c];
  if (!br){
    float spe = spe_b[c];
    #pragma unroll 8
    for (int i = 0; i < 64; ++i) spe += spe_w[c*64 + i] * mxb[b*64 + i];
    acc += clamp01(spe);
  } else {
    float z = spw[c] * cmb[b*4096 + pix] + spb[c];
    acc += clamp01(z);
  }
  out[(size_t)(b*64 + c)*NHW + pix] = acc;
}

// ---------------------------------------------------------------- lean simple pw body (64->64, flat args)
__device__ __forceinline__ void pw_simple(const float* __restrict__ in, const float* __restrict__ w,
    const float* __restrict__ bias, float* __restrict__ outf,
    hbf* __restrict__ tq, float tscale, hbf* __restrict__ cq, int ptile){
  __shared__ __align__(16) float Xs[64][32];
  __shared__ __align__(16) float Wt[64][64];    // [i][o]
  int t = threadIdx.x;
  int b = ptile >> 7; int n0 = (ptile & 127)*32;
  const float* inb = in + (size_t)b*64*NHW + n0;
  #pragma unroll
  for (int k = 0; k < 8; ++k){
    int i = k*8 + (t >> 5); int n = t & 31;
    Xs[i][n] = inb[(size_t)i*NHW + n];
  }
  #pragma unroll
  for (int k = 0; k < 16; ++k){
    int idx = k*256 + t; int o = idx & 63, i = idx >> 6;
    Wt[i][o] = w[(size_t)o*64 + i];
  }
  __syncthreads();
  int tn = t & 15, to = t >> 4;
  float a0x=0,a0y=0,a1x=0,a1y=0,a2x=0,a2y=0,a3x=0,a3y=0;
  #pragma unroll
  for (int i = 0; i < 64; ++i){
    const float2 xv = *(const float2*)&Xs[i][tn*2];
    const float4 wv = *(const float4*)&Wt[i][to*4];
    a0x += wv.x*xv.x; a0y += wv.x*xv.y;
    a1x += wv.y*xv.x; a1y += wv.y*xv.y;
    a2x += wv.z*xv.x; a2y += wv.z*xv.y;
    a3x += wv.w*xv.x; a3y += wv.w*xv.y;
  }
  float ax[4] = {a0x,a1x,a2x,a3x}, ay[4] = {a0y,a1y,a2y,a3y};
  #pragma unroll
  for (int oo = 0; oo < 4; ++oo){
    int o = to*4 + oo;
    float bv = bias[o];
    size_t obase = ((size_t)b*64 + o)*NHW + n0 + tn*2;
    float v0 = ax[oo] + bv, v1 = ay[oo] + bv;
    if (tq){
      int h = o >> 4, d = o & 15;
      size_t tb = ((size_t)(b*4 + h)*4096 + n0 + tn*2)*16 + d;
      tq[tb]    = __float2bfloat16(v0*tscale);
      tq[tb+16] = __float2bfloat16(v1*tscale);
    }
    if (cq){
      cq[obase+0] = __float2bfloat16(v0);
      cq[obase+1] = __float2bfloat16(v1);
    }
    if (outf){
      float2 vv; vv.x = v0; vv.y = v1;
      *(float2*)(outf + obase) = vv;
    }
  }
}

// two branch 1x1 convs in one launch: grid (256,1,2), flat args, scalar z-select
__global__ __launch_bounds__(256) void k_pwbr(const float* __restrict__ t1, const float* __restrict__ w0,
    const float* __restrict__ b0, float* __restrict__ hb,
    const float* __restrict__ tm, const float* __restrict__ w1,
    const float* __restrict__ b1, float* __restrict__ mb){
  int z = blockIdx.z;
  const float* in = z ? tm : t1;
  const float* w  = z ? w1 : w0;
  const float* bs = z ? b1 : b0;
  float* out      = z ? mb : hb;
  pw_simple(in, w, bs, out, nullptr, 1.f, nullptr, blockIdx.x);
}

// Q,K,V projections in one launch: grid (256,1,3), flat args, scalar z-select
__global__ __launch_bounds__(256) void k_pwqkv(const float* __restrict__ mb, const float* __restrict__ hb,
    const float* __restrict__ qw, const float* __restrict__ qb,
    const float* __restrict__ kw, const float* __restrict__ kb,
    const float* __restrict__ vw, const float* __restrict__ vb,
    hbf* __restrict__ qt, hbf* __restrict__ kt, hbf* __restrict__ vbf, float qs){
  int z = blockIdx.z;
  const float* in = (z == 0) ? mb : hb;
  const float* w  = (z == 0) ? qw : ((z == 1) ? kw : vw);
  const float* bs = (z == 0) ? qb : ((z == 1) ? kb : vb);
  hbf* tq = (z == 0) ? qt : ((z == 1) ? kt : nullptr);
  float ts = (z == 0) ? qs : 1.f;
  hbf* cq = (z == 2) ? vbf : nullptr;
  pw_simple(in, w, bs, nullptr, tq, ts, cq, blockIdx.x);
}

// ---------------------------------------------------------------- full-featured pw body (flat args)
// no-max flash combine: v = (sum_c Pacc_c) / (sum_c Pl_c)
__device__ __forceinline__ void pw_full(const float* __restrict__ in, const float* __restrict__ w,
    const float* __restrict__ bias, const float* __restrict__ lnw,
    const float* __restrict__ in2, float* __restrict__ add_out,
    const float* __restrict__ r1, const float* __restrict__ r2,
    float* __restrict__ outf, int OC,
    const float* __restrict__ Pacc, const float* __restrict__ Pl,
    int ptile, int oc0){
  __shared__ __align__(16) float Xs[64][32];
  __shared__ __align__(16) float Wt[64][64];    // [i][o]
  __shared__ float psum[8][32], psqs[8][32];
  __shared__ float invs[32];
  __shared__ float fs[4][32];                   // [h][n] 1/L
  int t = threadIdx.x;
  int b = ptile >> 7; int n0 = (ptile & 127)*32;
  const float* inb = in ? in + (size_t)b*64*NHW + n0 : nullptr;
  const float* inb2 = in2 ? in2 + (size_t)b*64*NHW + n0 : nullptr;
  float* aob = add_out ? add_out + (size_t)b*64*NHW + n0 : nullptr;
  if (Pacc){
    if (t < 128){
      int h = t >> 5, n = t & 31;
      int bh = b*4 + h, q = n0 + n;
      float L = Pl[(size_t)bh*4096 + q] + Pl[(size_t)(8+bh)*4096 + q]
              + Pl[(size_t)(16+bh)*4096 + q] + Pl[(size_t)(24+bh)*4096 + q];
      fs[h][n] = 1.0f / L;
    }
    __syncthreads();
  }
  float ps = 0.f, pss = 0.f;
  #pragma unroll
  for (int k = 0; k < 8; ++k){
    int i = k*8 + (t >> 5); int n = t & 31;
    float v;
    if (Pacc){
      int h = i >> 4, d = i & 15, bh = b*4 + h;
      const float* pb = Pacc + ((size_t)(bh*16 + d))*4096 + n0 + n;
      v = (pb[0] + pb[(size_t)SZ] + pb[(size_t)2*SZ] + pb[(size_t)3*SZ]) * fs[h][n];
    } else {
      v = inb[(size_t)i*NHW + n];
      if (inb2) v += inb2[(size_t)i*NHW + n];
    }
    Xs[i][n] = v;
    if (aob && oc0 == 0) aob[(size_t)i*NHW + n] = v;
    ps += v; pss += v*v;
  }
  if (lnw){ psum[t>>5][t&31] = ps; psqs[t>>5][t&31] = pss; }
  #pragma unroll
  for (int k = 0; k < 16; ++k){
    int idx = k*256 + t; int o = idx & 63, i = idx >> 6;
    float wv = w[(size_t)(oc0 + o)*64 + i];
    if (lnw) wv *= lnw[i];
    Wt[i][o] = wv;
  }
  __syncthreads();
  if (lnw){
    if (t < 32){
      float s1 = 0.f, s2 = 0.f;
      #pragma unroll
      for (int g = 0; g < 8; ++g){ s1 += psum[g][t]; s2 += psqs[g][t]; }
      float mu = s1*(1.0f/64.0f);
      float var = s2*(1.0f/64.0f) - mu*mu;
      invs[t] = rsqrtf(fmaxf(var, 0.f) + 1e-5f);
    }
    __syncthreads();
  }
  int tn = t & 15, to = t >> 4;
  float a0x=0,a0y=0,a1x=0,a1y=0,a2x=0,a2y=0,a3x=0,a3y=0;
  #pragma unroll
  for (int i = 0; i < 64; ++i){
    const float2 xv = *(const float2*)&Xs[i][tn*2];
    const float4 wv = *(const float4*)&Wt[i][to*4];
    a0x += wv.x*xv.x; a0y += wv.x*xv.y;
    a1x += wv.y*xv.x; a1y += wv.y*xv.y;
    a2x += wv.z*xv.x; a2y += wv.z*xv.y;
    a3x += wv.w*xv.x; a3y += wv.w*xv.y;
  }
  float sx = 1.f, sy = 1.f;
  if (lnw){ sx = invs[tn*2+0]; sy = invs[tn*2+1]; }
  float ax[4] = {a0x,a1x,a2x,a3x}, ay[4] = {a0y,a1y,a2y,a3y};
  #pragma unroll
  for (int oo = 0; oo < 4; ++oo){
    int o = oc0 + to*4 + oo;
    float bv = bias ? bias[o] : 0.f;
    size_t obase = ((size_t)b*OC + o)*NHW + n0 + tn*2;
    float v0 = ax[oo]*sx + bv, v1 = ay[oo]*sy + bv;
    if (r1){ v0 += r1[obase+0]; v1 += r1[obase+1]; }
    if (r2){ v0 += r2[obase+0]; v1 += r2[obase+1]; }
    if (outf){
      float2 vv; vv.x = v0; vv.y = v1;
      *(float2*)(outf + obase) = vv;
    }
  }
}

__global__ __launch_bounds__(256) void k_pw(const float* __restrict__ in, const float* __restrict__ w,
    const float* __restrict__ bias, const float* __restrict__ lnw,
    const float* __restrict__ in2, float* __restrict__ add_out,
    const float* __restrict__ r1, const float* __restrict__ r2,
    float* __restrict__ outf, int OC,
    const float* __restrict__ Pacc, const float* __restrict__ Pl){
  pw_full(in, w, bias, lnw, in2, add_out, r1, r2, outf, OC, Pacc, Pl, blockIdx.x, blockIdx.y*64);
}

// spectral ffn_in (z=0, OC=128) || restormer qkv (z=1, OC=192): grid (256,3,2)
__global__ __launch_bounds__(256) void k_pwfi(const float* __restrict__ xb, const float* __restrict__ w0,
    const float* __restrict__ ln0, float* __restrict__ tb,
    const float* __restrict__ hb, const float* __restrict__ w1, const float* __restrict__ ln1,
    const float* __restrict__ mb, float* __restrict__ yb, float* __restrict__ tb2){
  int z = blockIdx.z;
  int OC = z ? 192 : 128;
  int oc0 = blockIdx.y*64;
  if (oc0 >= OC) return;
  const float* in  = z ? hb : xb;
  const float* w   = z ? w1 : w0;
  const float* lnw = z ? ln1 : ln0;
  const float* in2 = z ? mb : nullptr;
  float* aout      = z ? yb : nullptr;
  float* outf      = z ? tb2 : tb;
  pw_full(in, w, nullptr, lnw, in2, aout, nullptr, nullptr, outf, OC, nullptr, nullptr, blockIdx.x, oc0);
}

// spectral ffn_out (blocks 0..255) || restormer rnorm (blocks 256..511)
__global__ __launch_bounds__(256) void k_pwrn(const float* __restrict__ g1, const float* __restrict__ w,
    const float* __restrict__ xb, float* __restrict__ xout,
    const float* __restrict__ qkv, float* __restrict__ norms){
  int bb = blockIdx.x;
  if (bb < NPIX/32){
    pw_full(g1, w, nullptr, nullptr, nullptr, nullptr, xb, nullptr, xout, 64, nullptr, nullptr, bb, 0);
  } else {
    int blk = bb - NPIX/32; int b = blk >> 7, r = blk & 127;
    int t = threadIdx.x;
    const float* p = qkv + ((size_t)b*192 + r)*NHW;
    float ss = 0.f;
    for (int i = t*4; i < NHW; i += 1024){
      float4 v = *(const float4*)(p + i);
      ss += v.x*v.x + v.y*v.y + v.z*v.z + v.w*v.w;
    }
    #pragma unroll
    for (int off = 32; off; off >>= 1) ss += __shfl_xor(ss, off);
    __shared__ float sm[4];
    if ((t & 63) == 0) sm[t >> 6] = ss;
    __syncthreads();
    if (t == 0) norms[blk] = fmaxf(sqrtf(sm[0]+sm[1]+sm[2]+sm[3]), 1e-12f);
  }
}

// ---------------------------------------------------------------- MFMA flash cross-attention, hd=16, n=4096
// grid 2048 = qt(64) x bh(8) x chunk(4); block 256 = 4 waves; wave = 16 queries.
// No-max softmax: Qt pre-scaled by 0.25*log2e, P = exp2(score) unnormalized
// (scores bounded; fp32 has 2^127 headroom). Combine: O = sum Pacc / sum Pl.
// [r21-proven form: single acc, 3 loads in flight, VGPR 24, occ ~78%]
__global__ __launch_bounds__(256) void k_mfa(const hbf* __restrict__ Qt, const hbf* __restrict__ Kt,
                                             const hbf* __restrict__ Vb, float* __restrict__ Pacc,
                                             float* __restrict__ Pl){
  int blk = blockIdx.x;
  int qt = blk & 63; int bh = (blk >> 6) & 7; int c = blk >> 9;   // c 0..3
  int t = threadIdx.x;
  int w = t >> 6, l = t & 63;
  int lg = l >> 4, lq = l & 15;
  int q0 = qt*64 + w*16;
  int rho = ((lq >> 2) << 3) + (lq & 3);        // 0-3,8-11,16-19,24-27
  bf16x8 qf = {};
  if (lg < 2) qf = *(const bf16x8*)&Qt[((size_t)bh*4096 + q0 + lq)*16 + lg*8];
  f32x4 acc = {0.f, 0.f, 0.f, 0.f};
  float lsum = 0.f;
  const hbf* Ktb = Kt + ((size_t)bh*4096 + c*1024)*16;
  const hbf* Vbb = Vb + (size_t)bh*16*4096 + c*1024;
  for (int kb = 0; kb < 1024; kb += 32){
    bf16x8 kf0 = {}, kf1 = {};
    if (lg < 2){
      kf0 = *(const bf16x8*)&Ktb[(size_t)(kb + rho)*16 + lg*8];
      kf1 = *(const bf16x8*)&Ktb[(size_t)(kb + rho + 4)*16 + lg*8];
    }
    f32x4 z = {0.f, 0.f, 0.f, 0.f};
    f32x4 s0 = __builtin_amdgcn_mfma_f32_16x16x32_bf16(kf0, qf, z, 0, 0, 0);
    f32x4 s1 = __builtin_amdgcn_mfma_f32_16x16x32_bf16(kf1, qf, z, 0, 0, 0);
    float p[8];
    p[0]=s0[0]; p[1]=s0[1]; p[2]=s0[2]; p[3]=s0[3];   // keys lg*8+0..3
    p[4]=s1[0]; p[5]=s1[1]; p[6]=s1[2]; p[7]=s1[3];   // keys lg*8+4..7
    #pragma unroll
    for (int i = 0; i < 8; ++i){ p[i] = fexp2(p[i]); lsum += p[i]; }
    bf16x8 pf;
    #pragma unroll
    for (int j = 0; j < 8; ++j){
      hbf hb = __float2bfloat16(p[j]);
      pf[j] = *reinterpret_cast<short*>(&hb);
    }
    bf16x8 vf = *(const bf16x8*)&Vbb[(size_t)lq*4096 + kb + lg*8];
    acc = __builtin_amdgcn_mfma_f32_16x16x32_bf16(vf, pf, acc, 0, 0, 0);
  }
  // reduce per-lane lsum across the 4 lane groups (same query lq)
  lsum += __shfl_xor(lsum, 16);
  lsum += __shfl_xor(lsum, 32);
  int pb = c*8 + bh;
  if (lg == 0) Pl[(size_t)pb*4096 + q0 + lq] = lsum;
  #pragma unroll
  for (int r = 0; r < 4; ++r){
    int d = lg*4 + r;
    Pacc[((size_t)pb*16 + d)*4096 + q0 + lq] = acc[r];
  }
}

// ---------------------------------------------------------------- FFN dw3x3 + chunk + gelu gate (128->64)
__device__ __forceinline__ void dwgate_body(const float* __restrict__ in, const float* __restrict__ w,
                                            float* __restrict__ out, int g){
  int pix = g & 4095; int c = (g >> 12) & 63; int b = g >> 18;
  int y = pix >> 6, x = pix & 63;
  const float* p1 = in + ((size_t)b*128 + c)*NHW;
  const float* p2 = in + ((size_t)b*128 + 64 + c)*NHW;
  float w1[9], w2[9];
  #pragma unroll
  for (int i = 0; i < 9; ++i){ w1[i] = w[c*9+i]; w2[i] = w[(64+c)*9+i]; }
  float a = 0.f, bb = 0.f;
  #pragma unroll
  for (int ky = -1; ky <= 1; ++ky){
    int yy = y + ky; if ((unsigned)yy >= 64u) continue;
    #pragma unroll
    for (int kx = -1; kx <= 1; ++kx){
      int xx = x + kx; if ((unsigned)xx >= 64u) continue;
      int off = yy*64 + xx; int wi = (ky+1)*3 + (kx+1);
      a  += p1[off]*w1[wi];
      bb += p2[off]*w2[wi];
    }
  }
  float gl = 0.5f*a*(1.0f + erff(a*0.70710678118654752f));   // exact gelu
  out[g] = gl*bb;
}

__global__ __launch_bounds__(256) void k_dwgate(const float* __restrict__ in, const float* __restrict__ w,
                                                float* __restrict__ out){
  dwgate_body(in, w, out, blockIdx.x*256 + threadIdx.x);
}

// dwgate (spectral) || dw192 (restormer qkv) in one launch, scalar block split
__global__ __launch_bounds__(256) void k_dwg2(const float* __restrict__ inG, const float* __restrict__ wG,
                                              float* __restrict__ outG,
                                              const float* __restrict__ inD, const float* __restrict__ wD,
                                              float* __restrict__ outD){
  int bb = blockIdx.x;
  if (bb < SZ/256){
    dwgate_body(inG, wG, outG, bb*256 + threadIdx.x);
  } else {
    int g = (bb - SZ/256)*256 + threadIdx.x;    // B*192*4096
    int pix = g & 4095; int bc = g >> 12; int c = bc % 192;
    int y = pix >> 6, x = pix & 63;
    const float* p = inD + (size_t)bc*NHW;
    float wf[9];
    #pragma unroll
    for (int i = 0; i < 9; ++i) wf[i] = wD[c*9+i];
    float acc = 0.f;
    #pragma unroll
    for (int ky = -1; ky <= 1; ++ky){
      int yy = y + ky; if ((unsigned)yy >= 64u) continue;
      #pragma unroll
      for (int kx = -1; kx <= 1; ++kx){
        int xx = x + kx; if ((unsigned)xx >= 64u) continue;
        acc += p[yy*64 + xx]*wf[(ky+1)*3 + (kx+1)];
      }
    }
    outD[g] = acc;
  }
}

// ---------------------------------------------------------------- restormer channel attention
__global__ __launch_bounds__(256) void k_rattn2(const float* __restrict__ qkv, const float* __restrict__ norms,
                                                const float* __restrict__ temp, float* __restrict__ out){
  int blk = blockIdx.x; int rq = blk & 15, h = (blk >> 4) & 3, b = blk >> 6;
  int t = threadIdx.x;
  const float* bq = qkv + ((size_t)b*192 + h*16 + rq)*NHW;
  const float* bk = qkv + ((size_t)b*192 + 64 + h*16)*NHW;
  float p[16];
  #pragma unroll
  for (int rk = 0; rk < 16; ++rk) p[rk] = 0.f;
  for (int n = t*4; n < NHW; n += 1024){
    float4 qv4 = *(const float4*)(bq + n);
    #pragma unroll
    for (int rk = 0; rk < 16; ++rk){
      float4 kv = *(const float4*)(bk + (size_t)rk*NHW + n);
      p[rk] += qv4.x*kv.x + qv4.y*kv.y + qv4.z*kv.z + qv4.w*kv.w;
    }
  }
  #pragma unroll
  for (int rk = 0; rk < 16; ++rk)
    #pragma unroll
    for (int off = 32; off; off >>= 1) p[rk] += __shfl_xor(p[rk], off);
  __shared__ float red[4][16];
  if ((t & 63) == 0){
    int wv_ = t >> 6;
    #pragma unroll
    for (int rk = 0; rk < 16; ++rk) red[wv_][rk] = p[rk];
  }
  __syncthreads();
  __shared__ float attn[16];
  if (t == 0){
    float nq = norms[b*128 + h*16 + rq];
    float tp = temp[h];
    float e[16]; float mm = -1e30f;
    #pragma unroll
    for (int rk = 0; rk < 16; ++rk){
      float dot = red[0][rk]+red[1][rk]+red[2][rk]+red[3][rk];
      e[rk] = dot/(nq*norms[b*128 + 64 + h*16 + rk]) * tp;
      mm = fmaxf(mm, e[rk]);
    }
    float ssum = 0.f;
    #pragma unroll
    for (int rk = 0; rk < 16; ++rk){ e[rk] = __expf(e[rk]-mm); ssum += e[rk]; }
    float is = 1.f/ssum;
    #pragma unroll
    for (int rk = 0; rk < 16; ++rk) attn[rk] = e[rk]*is;
  }
  __syncthreads();
  float aw[16];
  #pragma unroll
  for (int rk = 0; rk < 16; ++rk) aw[rk] = attn[rk];
  const float* vb = qkv + ((size_t)b*192 + 128 + h*16)*NHW;
  float* ob = out + ((size_t)b*64 + h*16 + rq)*NHW;
  for (int n = t*4; n < NHW; n += 1024){
    float4 o; o.x = 0.f; o.y = 0.f; o.z = 0.f; o.w = 0.f;
    #pragma unroll
    for (int rk = 0; rk < 16; ++rk){
      float4 v = *(const float4*)(vb + (size_t)rk*NHW + n);
      o.x += aw[rk]*v.x; o.y += aw[rk]*v.y; o.z += aw[rk]*v.z; o.w += aw[rk]*v.w;
    }
    *(float4*)(ob + n) = o;
  }
}

// ================================================================ host
extern "C" void kernel_launch(void* const* d_in, const int* in_sizes, int n_in,
                              void* d_out, int out_size, void* d_ws, size_t ws_size,
                              hipStream_t stream){
  const float* hsi_f0     = (const float*)d_in[0];
  const float* msi_f0     = (const float*)d_in[1];
  const float* hsi_fi     = (const float*)d_in[2];
  const float* msi_fi     = (const float*)d_in[3];
  const float* sp_mlp_w   = (const float*)d_in[4];
  const float* sp_mlp_b   = (const float*)d_in[5];
  const float* spe_mlp_w  = (const float*)d_in[6];
  const float* spe_mlp_b  = (const float*)d_in[7];
  const float* spa_dw_w   = (const float*)d_in[8];
  const float* spa_dw_b   = (const float*)d_in[9];
  const float* spa_pw_w   = (const float*)d_in[10];
  const float* spa_pw_b   = (const float*)d_in[11];
  const float* spe_dw_w   = (const float*)d_in[12];
  const float* spe_dw_b   = (const float*)d_in[13];
  const float* spe_pw_w   = (const float*)d_in[14];
  const float* spe_pw_b   = (const float*)d_in[15];
  const float* sb_q_w     = (const float*)d_in[16];
  const float* sb_q_b     = (const float*)d_in[17];
  const float* sb_k_w     = (const float*)d_in[18];
  const float* sb_k_b     = (const float*)d_in[19];
  const float* sb_v_w     = (const float*)d_in[20];
  const float* sb_v_b     = (const float*)d_in[21];
  const float* sb_o_w     = (const float*)d_in[22];
  const float* sb_o_b     = (const float*)d_in[23];
  const float* sb_norm2_w = (const float*)d_in[24];
  const float* sb_ffn_in_w  = (const float*)d_in[25];
  const float* sb_ffn_dw_w  = (const float*)d_in[26];
  const float* sb_ffn_out_w = (const float*)d_in[27];
  const float* rb_norm1_w = (const float*)d_in[28];
  const float* rb_temp    = (const float*)d_in[29];
  const float* rb_qkv_w   = (const float*)d_in[30];
  const float* rb_qkv_dw_w= (const float*)d_in[31];
  const float* rb_proj_w  = (const float*)d_in[32];
  const float* rb_norm2_w = (const float*)d_in[33];
  const float* rb_ffn_in_w  = (const float*)d_in[34];
  const float* rb_ffn_dw_w  = (const float*)d_in[35];
  const float* rb_ffn_out_w = (const float*)d_in[36];

  float* W   = (float*)d_ws;
  float* Hb  = W;                 // hsi branch output      [B][64][HW]
  float* Mb  = W + (size_t)SZ;    // msi branch output; later: spectral gate G1
  float* Xb  = W + (size_t)2*SZ;  // x1
  float* Yb  = W + (size_t)3*SZ;  // y
  float* T1  = W + (size_t)4*SZ;  // dw-hsi out; QKV[0] later; rb gate out at end
  float* QKV = T1;                // 3*SZ contiguous (4SZ..7SZ) for restormer qkv
  float* TB  = W + (size_t)7*SZ;  // dw-msi out; 128-ch ffn buffer / attn out
  float* Tm  = TB;                // msi dw3 output (dead before TB reused)
  float* TB2 = W + (size_t)9*SZ;  // 3*SZ (192-ch pre-dw qkv)
  float* Pacc= W + (size_t)7*SZ;         // 4*SZ flash partial acc
  float* Pl  = W + (size_t)11*SZ;        // 131072
  float* mxb = W + (size_t)12*SZ;        // 128
  float* cmb = mxb + 256;                // 8192
  float* normb = W + (size_t)12*SZ + 9216; // 256
  // bf16 attention operand buffers in the 5SZ..7SZ region
  hbf* Qt  = (hbf*)(W + (size_t)5*SZ);            // [8][4096][16] bf16, pre-scaled 0.25*log2e
  hbf* Kt  = Qt + (size_t)8*4096*16;              // [8][4096][16]
  hbf* Vbf = Kt + (size_t)8*4096*16;              // [8][16][4096]
  float* G1 = Mb;                 // spectral gate output (Mb dead by then)

  float* outf = (float*)d_out;
  const float QS = 0.25f*LOG2E;

  // reductions (max-over-HW || channel-mean), one launch
  k_maxmean<<<NB*NC + NPIX/256, 256, 0, stream>>>(hsi_fi, mxb, msi_fi, cmb);
  // both depthwise branches + score MLPs, one launch
  k_dw3b<<<2*SZ/256, 256, 0, stream>>>(hsi_f0, spe_dw_w, spe_dw_b, mxb, spe_mlp_w, spe_mlp_b,
                                       msi_f0, spa_dw_w, spa_dw_b, cmb, sp_mlp_w, sp_mlp_b,
                                       T1, Tm);
  // branch 1x1 convs, one launch
  k_pwbr<<<dim3(NPIX/32,1,2), 256, 0, stream>>>(T1, spe_pw_w, spe_pw_b, Hb,
                                                Tm, spa_pw_w, spa_pw_b, Mb);
  // Q,K,V projections, one launch
  k_pwqkv<<<dim3(NPIX/32,1,3), 256, 0, stream>>>(Mb, Hb, sb_q_w, sb_q_b, sb_k_w, sb_k_b,
                                                 sb_v_w, sb_v_b, Qt, Kt, Vbf, QS);
  k_mfa<<<2048, 256, 0, stream>>>(Qt, Kt, Vbf, Pacc, Pl);
  // o-proj with fused no-max flash-combine input (+msi residual)
  k_pw<<<dim3(NPIX/32,1), 256, 0, stream>>>(nullptr, sb_o_w, sb_o_b, nullptr, nullptr, nullptr, Mb, nullptr, Xb, 64, Pacc, Pl);
  // spectral ffn_in (LN fused) || restormer qkv (y=Hb+Mb in-staging, LN fused), one launch
  k_pwfi<<<dim3(NPIX/32,3,2), 256, 0, stream>>>(Xb, sb_ffn_in_w, sb_norm2_w, TB,
                                                Hb, rb_qkv_w, rb_norm1_w, Mb, Yb, TB2);
  // spectral dw-gate || restormer qkv dw3x3 (gate out -> G1=Mb, now dead)
  k_dwg2<<<SZ/256 + 3*SZ/256, 256, 0, stream>>>(TB, sb_ffn_dw_w, G1, TB2, rb_qkv_dw_w, QKV);
  // spectral ffn_out (x1 = Xb + out) || restormer rnorm, one launch
  k_pwrn<<<NPIX/32 + 256, 256, 0, stream>>>(G1, sb_ffn_out_w, Xb, Xb, QKV, normb);
  // restormer attention
  k_rattn2<<<128, 256, 0, stream>>>(QKV, normb, rb_temp, TB);
  k_pw<<<dim3(NPIX/32,1), 256, 0, stream>>>(TB, rb_proj_w, nullptr, nullptr, nullptr, nullptr, Yb, nullptr, Yb, 64, nullptr, nullptr);
  // restormer FFN + final combine: out = x1 + (y + ffn(ln(y)))
  k_pw<<<dim3(NPIX/32,2), 256, 0, stream>>>(Yb, rb_ffn_in_w, nullptr, rb_norm2_w, nullptr, nullptr, nullptr, nullptr, TB, 128, nullptr, nullptr);
  k_dwgate<<<SZ/256, 256, 0, stream>>>(TB, rb_ffn_dw_w, T1);
  k_pw<<<dim3(NPIX/32,1), 256, 0, stream>>>(T1, rb_ffn_out_w, nullptr, nullptr, nullptr, nullptr, Xb, Yb, outf, 64, nullptr, nullptr);
}

// Round 25
// 226.840 us; speedup vs baseline: 1.0666x; 1.0011x over previous
//
#include <hip/hip_runtime.h>
#include <hip/hip_bf16.h>

#define NB 2
#define NC 64
#define NHW 4096
#define NPIX (NB*NHW)          // 8192
#define SZ   (NB*NC*NHW)       // 524288 floats per 64-ch fp32 tensor
#define LOG2E 1.4426950408889634f

typedef __attribute__((ext_vector_type(8))) short bf16x8;
typedef __attribute__((ext_vector_type(4))) float f32x4;
typedef __hip_bfloat16 hbf;

__device__ __forceinline__ float clamp01(float v){ return fminf(fmaxf(v, 0.f), 1.f); }
__device__ __forceinline__ float fexp2(float x){ return __builtin_amdgcn_exp2f(x); }  // raw v_exp_f32

// ---------------------------------------------------------------- fused reductions: max-over-HW (blocks 0..127) || channel-mean (blocks 128..159)
// pwrn-proven pattern: scalar blockIdx split, BOTH branches contain a barrier.
__global__ __launch_bounds__(256) void k_maxmean(const float* __restrict__ hsi_fi, float* __restrict__ mx,
                                                 const float* __restrict__ msi_fi, float* __restrict__ cm){
  int bb = blockIdx.x; int t = threadIdx.x;
  __shared__ float sm[4];
  if (bb < NB*NC){
    const float* p = hsi_fi + (size_t)bb*NHW;
    float m = -1e30f;
    for (int n = t; n < NHW; n += 256) m = fmaxf(m, p[n]);
    #pragma unroll
    for (int off = 32; off; off >>= 1) m = fmaxf(m, __shfl_xor(m, off));
    if ((t & 63) == 0) sm[t >> 6] = m;
    __syncthreads();
    if (t == 0) mx[bb] = fmaxf(fmaxf(sm[0], sm[1]), fmaxf(sm[2], sm[3]));
  } else {
    int p = (bb - NB*NC)*256 + t;               // 0..8191
    int b = p >> 12, n = p & 4095;
    const float* base = msi_fi + (size_t)b*NC*NHW + n;
    float s = 0.f;
    #pragma unroll
    for (int c = 0; c < 64; ++c) s += base[c*NHW];
    __syncthreads();                            // barrier parity with max branch
    cm[p] = s * (1.0f/64.0f);
  }
}

// ---------------------------------------------------------------- both depthwise 3x3 branches + score MLPs, one launch
__global__ __launch_bounds__(256) void k_dw3b(const float* __restrict__ hsi0, const float* __restrict__ wh,
    const float* __restrict__ bh, const float* __restrict__ mxb,
    const float* __restrict__ spe_w, const float* __restrict__ spe_b,
    const float* __restrict__ msi0, const float* __restrict__ wm, const float* __restrict__ bm,
    const float* __restrict__ cmb, const float* __restrict__ spw, const float* __restrict__ spb,
    float* __restrict__ out0, float* __restrict__ out1){
  int bb = blockIdx.x;                    // 0..4095
  int br = bb >= (SZ/256);                // scalar branch
  int bbl = br ? bb - SZ/256 : bb;        // 0..2047
  int b = bbl >> 10;                      // scalar
  int c = (bbl >> 4) & 63;                // scalar
  int t = threadIdx.x;
  int pix = (bbl & 15)*256 + t;
  const float* in = br ? msi0 : hsi0;
  const float* w  = br ? wm : wh;
  const float* bs = br ? bm : bh;
  float* out      = br ? out1 : out0;
  int y = pix >> 6, x = pix & 63;
  const float* base = in + (size_t)(b*64 + c)*NHW;
  float wf[9];
  #pragma unroll
  for (int i = 0; i < 9; ++i) wf[i] = w[c*9 + i];
  float acc = 0.f;
  #pragma unroll
  for (int ky = -1; ky <= 1; ++ky){
    int yy = y + ky; if ((unsigned)yy >= 64u) continue;
    #pragma unroll
    for (int kx = -1; kx <= 1; ++kx){
      int xx = x + kx; if ((unsigned)xx >= 64u) continue;
      acc += base[yy*64 + xx] * wf[(ky+1)*3 + (kx+1)];
    }
  }
  acc += bs[c];
  if (!br){
    float spe = spe_b[c];
    #pragma unroll 8
    for (int i = 0; i < 64; ++i) spe += spe_w[c*64 + i] * mxb[b*64 + i];
    acc += clamp01(spe);
  } else {
    float z = spw[c] * cmb[b*4096 + pix] + spb[c];
    acc += clamp01(z);
  }
  out[(size_t)(b*64 + c)*NHW + pix] = acc;
}

// ---------------------------------------------------------------- lean simple pw body (64->64, flat args)
__device__ __forceinline__ void pw_simple(const float* __restrict__ in, const float* __restrict__ w,
    const float* __restrict__ bias, float* __restrict__ outf,
    hbf* __restrict__ tq, float tscale, hbf* __restrict__ cq, int ptile){
  __shared__ __align__(16) float Xs[64][32];
  __shared__ __align__(16) float Wt[64][64];    // [i][o]
  int t = threadIdx.x;
  int b = ptile >> 7; int n0 = (ptile & 127)*32;
  const float* inb = in + (size_t)b*64*NHW + n0;
  #pragma unroll
  for (int k = 0; k < 8; ++k){
    int i = k*8 + (t >> 5); int n = t & 31;
    Xs[i][n] = inb[(size_t)i*NHW + n];
  }
  #pragma unroll
  for (int k = 0; k < 16; ++k){
    int idx = k*256 + t; int o = idx & 63, i = idx >> 6;
    Wt[i][o] = w[(size_t)o*64 + i];
  }
  __syncthreads();
  int tn = t & 15, to = t >> 4;
  float a0x=0,a0y=0,a1x=0,a1y=0,a2x=0,a2y=0,a3x=0,a3y=0;
  #pragma unroll
  for (int i = 0; i < 64; ++i){
    const float2 xv = *(const float2*)&Xs[i][tn*2];
    const float4 wv = *(const float4*)&Wt[i][to*4];
    a0x += wv.x*xv.x; a0y += wv.x*xv.y;
    a1x += wv.y*xv.x; a1y += wv.y*xv.y;
    a2x += wv.z*xv.x; a2y += wv.z*xv.y;
    a3x += wv.w*xv.x; a3y += wv.w*xv.y;
  }
  float ax[4] = {a0x,a1x,a2x,a3x}, ay[4] = {a0y,a1y,a2y,a3y};
  #pragma unroll
  for (int oo = 0; oo < 4; ++oo){
    int o = to*4 + oo;
    float bv = bias[o];
    size_t obase = ((size_t)b*64 + o)*NHW + n0 + tn*2;
    float v0 = ax[oo] + bv, v1 = ay[oo] + bv;
    if (tq){
      int h = o >> 4, d = o & 15;
      size_t tb = ((size_t)(b*4 + h)*4096 + n0 + tn*2)*16 + d;
      tq[tb]    = __float2bfloat16(v0*tscale);
      tq[tb+16] = __float2bfloat16(v1*tscale);
    }
    if (cq){
      cq[obase+0] = __float2bfloat16(v0);
      cq[obase+1] = __float2bfloat16(v1);
    }
    if (outf){
      float2 vv; vv.x = v0; vv.y = v1;
      *(float2*)(outf + obase) = vv;
    }
  }
}

// two branch 1x1 convs in one launch: grid (256,1,2), flat args, scalar z-select
__global__ __launch_bounds__(256) void k_pwbr(const float* __restrict__ t1, const float* __restrict__ w0,
    const float* __restrict__ b0, float* __restrict__ hb,
    const float* __restrict__ tm, const float* __restrict__ w1,
    const float* __restrict__ b1, float* __restrict__ mb){
  int z = blockIdx.z;
  const float* in = z ? tm : t1;
  const float* w  = z ? w1 : w0;
  const float* bs = z ? b1 : b0;
  float* out      = z ? mb : hb;
  pw_simple(in, w, bs, out, nullptr, 1.f, nullptr, blockIdx.x);
}

// Q,K,V projections in one launch: grid (256,1,3), flat args, scalar z-select
__global__ __launch_bounds__(256) void k_pwqkv(const float* __restrict__ mb, const float* __restrict__ hb,
    const float* __restrict__ qw, const float* __restrict__ qb,
    const float* __restrict__ kw, const float* __restrict__ kb,
    const float* __restrict__ vw, const float* __restrict__ vb,
    hbf* __restrict__ qt, hbf* __restrict__ kt, hbf* __restrict__ vbf, float qs){
  int z = blockIdx.z;
  const float* in = (z == 0) ? mb : hb;
  const float* w  = (z == 0) ? qw : ((z == 1) ? kw : vw);
  const float* bs = (z == 0) ? qb : ((z == 1) ? kb : vb);
  hbf* tq = (z == 0) ? qt : ((z == 1) ? kt : nullptr);
  float ts = (z == 0) ? qs : 1.f;
  hbf* cq = (z == 2) ? vbf : nullptr;
  pw_simple(in, w, bs, nullptr, tq, ts, cq, blockIdx.x);
}

// ---------------------------------------------------------------- full-featured pw body (flat args)
// no-max flash combine: v = (sum_c Pacc_c) / (sum_c Pl_c)
__device__ __forceinline__ void pw_full(const float* __restrict__ in, const float* __restrict__ w,
    const float* __restrict__ bias, const float* __restrict__ lnw,
    const float* __restrict__ in2, float* __restrict__ add_out,
    const float* __restrict__ r1, const float* __restrict__ r2,
    float* __restrict__ outf, int OC,
    const float* __restrict__ Pacc, const float* __restrict__ Pl,
    int ptile, int oc0){
  __shared__ __align__(16) float Xs[64][32];
  __shared__ __align__(16) float Wt[64][64];    // [i][o]
  __shared__ float psum[8][32], psqs[8][32];
  __shared__ float invs[32];
  __shared__ float fs[4][32];                   // [h][n] 1/L
  int t = threadIdx.x;
  int b = ptile >> 7; int n0 = (ptile & 127)*32;
  const float* inb = in ? in + (size_t)b*64*NHW + n0 : nullptr;
  const float* inb2 = in2 ? in2 + (size_t)b*64*NHW + n0 : nullptr;
  float* aob = add_out ? add_out + (size_t)b*64*NHW + n0 : nullptr;
  if (Pacc){
    if (t < 128){
      int h = t >> 5, n = t & 31;
      int bh = b*4 + h, q = n0 + n;
      float L = Pl[(size_t)bh*4096 + q] + Pl[(size_t)(8+bh)*4096 + q]
              + Pl[(size_t)(16+bh)*4096 + q] + Pl[(size_t)(24+bh)*4096 + q];
      fs[h][n] = 1.0f / L;
    }
    __syncthreads();
  }
  float ps = 0.f, pss = 0.f;
  #pragma unroll
  for (int k = 0; k < 8; ++k){
    int i = k*8 + (t >> 5); int n = t & 31;
    float v;
    if (Pacc){
      int h = i >> 4, d = i & 15, bh = b*4 + h;
      const float* pb = Pacc + ((size_t)(bh*16 + d))*4096 + n0 + n;
      v = (pb[0] + pb[(size_t)SZ] + pb[(size_t)2*SZ] + pb[(size_t)3*SZ]) * fs[h][n];
    } else {
      v = inb[(size_t)i*NHW + n];
      if (inb2) v += inb2[(size_t)i*NHW + n];
    }
    Xs[i][n] = v;
    if (aob && oc0 == 0) aob[(size_t)i*NHW + n] = v;
    ps += v; pss += v*v;
  }
  if (lnw){ psum[t>>5][t&31] = ps; psqs[t>>5][t&31] = pss; }
  #pragma unroll
  for (int k = 0; k < 16; ++k){
    int idx = k*256 + t; int o = idx & 63, i = idx >> 6;
    float wv = w[(size_t)(oc0 + o)*64 + i];
    if (lnw) wv *= lnw[i];
    Wt[i][o] = wv;
  }
  __syncthreads();
  if (lnw){
    if (t < 32){
      float s1 = 0.f, s2 = 0.f;
      #pragma unroll
      for (int g = 0; g < 8; ++g){ s1 += psum[g][t]; s2 += psqs[g][t]; }
      float mu = s1*(1.0f/64.0f);
      float var = s2*(1.0f/64.0f) - mu*mu;
      invs[t] = rsqrtf(fmaxf(var, 0.f) + 1e-5f);
    }
    __syncthreads();
  }
  int tn = t & 15, to = t >> 4;
  float a0x=0,a0y=0,a1x=0,a1y=0,a2x=0,a2y=0,a3x=0,a3y=0;
  #pragma unroll
  for (int i = 0; i < 64; ++i){
    const float2 xv = *(const float2*)&Xs[i][tn*2];
    const float4 wv = *(const float4*)&Wt[i][to*4];
    a0x += wv.x*xv.x; a0y += wv.x*xv.y;
    a1x += wv.y*xv.x; a1y += wv.y*xv.y;
    a2x += wv.z*xv.x; a2y += wv.z*xv.y;
    a3x += wv.w*xv.x; a3y += wv.w*xv.y;
  }
  float sx = 1.f, sy = 1.f;
  if (lnw){ sx = invs[tn*2+0]; sy = invs[tn*2+1]; }
  float ax[4] = {a0x,a1x,a2x,a3x}, ay[4] = {a0y,a1y,a2y,a3y};
  #pragma unroll
  for (int oo = 0; oo < 4; ++oo){
    int o = oc0 + to*4 + oo;
    float bv = bias ? bias[o] : 0.f;
    size_t obase = ((size_t)b*OC + o)*NHW + n0 + tn*2;
    float v0 = ax[oo]*sx + bv, v1 = ay[oo]*sy + bv;
    if (r1){ v0 += r1[obase+0]; v1 += r1[obase+1]; }
    if (r2){ v0 += r2[obase+0]; v1 += r2[obase+1]; }
    if (outf){
      float2 vv; vv.x = v0; vv.y = v1;
      *(float2*)(outf + obase) = vv;
    }
  }
}

__global__ __launch_bounds__(256) void k_pw(const float* __restrict__ in, const float* __restrict__ w,
    const float* __restrict__ bias, const float* __restrict__ lnw,
    const float* __restrict__ in2, float* __restrict__ add_out,
    const float* __restrict__ r1, const float* __restrict__ r2,
    float* __restrict__ outf, int OC,
    const float* __restrict__ Pacc, const float* __restrict__ Pl){
  pw_full(in, w, bias, lnw, in2, add_out, r1, r2, outf, OC, Pacc, Pl, blockIdx.x, blockIdx.y*64);
}

// spectral ffn_in (z=0, OC=128) || restormer qkv (z=1, OC=192): grid (256,3,2)
__global__ __launch_bounds__(256) void k_pwfi(const float* __restrict__ xb, const float* __restrict__ w0,
    const float* __restrict__ ln0, float* __restrict__ tb,
    const float* __restrict__ hb, const float* __restrict__ w1, const float* __restrict__ ln1,
    const float* __restrict__ mb, float* __restrict__ yb, float* __restrict__ tb2){
  int z = blockIdx.z;
  int OC = z ? 192 : 128;
  int oc0 = blockIdx.y*64;
  if (oc0 >= OC) return;
  const float* in  = z ? hb : xb;
  const float* w   = z ? w1 : w0;
  const float* lnw = z ? ln1 : ln0;
  const float* in2 = z ? mb : nullptr;
  float* aout      = z ? yb : nullptr;
  float* outf      = z ? tb2 : tb;
  pw_full(in, w, nullptr, lnw, in2, aout, nullptr, nullptr, outf, OC, nullptr, nullptr, blockIdx.x, oc0);
}

// spectral ffn_out (blocks 0..255) || restormer rnorm (blocks 256..511)
__global__ __launch_bounds__(256) void k_pwrn(const float* __restrict__ g1, const float* __restrict__ w,
    const float* __restrict__ xb, float* __restrict__ xout,
    const float* __restrict__ qkv, float* __restrict__ norms){
  int bb = blockIdx.x;
  if (bb < NPIX/32){
    pw_full(g1, w, nullptr, nullptr, nullptr, nullptr, xb, nullptr, xout, 64, nullptr, nullptr, bb, 0);
  } else {
    int blk = bb - NPIX/32; int b = blk >> 7, r = blk & 127;
    int t = threadIdx.x;
    const float* p = qkv + ((size_t)b*192 + r)*NHW;
    float ss = 0.f;
    for (int i = t*4; i < NHW; i += 1024){
      float4 v = *(const float4*)(p + i);
      ss += v.x*v.x + v.y*v.y + v.z*v.z + v.w*v.w;
    }
    #pragma unroll
    for (int off = 32; off; off >>= 1) ss += __shfl_xor(ss, off);
    __shared__ float sm[4];
    if ((t & 63) == 0) sm[t >> 6] = ss;
    __syncthreads();
    if (t == 0) norms[blk] = fmaxf(sqrtf(sm[0]+sm[1]+sm[2]+sm[3]), 1e-12f);
  }
}

// ---------------------------------------------------------------- MFMA flash cross-attention, hd=16, n=4096
// grid 2048 = qt(64) x bh(8) x chunk(4); block 256 = 4 waves; wave = 16 queries.
// No-max softmax (Qt pre-scaled 0.25*log2e). lsum computed on the MATRIX pipe:
// lacc = mfma(ones, pf, lacc) -> every row of C equals sum_k P[k][q], covering
// all 32 keys (B-frag spans all lane groups) -> no per-iter VALU adds, no
// end-of-loop shfl reduction, and lsum rounding matches the numerator's bf16 P.
__global__ __launch_bounds__(256) void k_mfa(const hbf* __restrict__ Qt, const hbf* __restrict__ Kt,
                                             const hbf* __restrict__ Vb, float* __restrict__ Pacc,
                                             float* __restrict__ Pl){
  int blk = blockIdx.x;
  int qt = blk & 63; int bh = (blk >> 6) & 7; int c = blk >> 9;   // c 0..3
  int t = threadIdx.x;
  int w = t >> 6, l = t & 63;
  int lg = l >> 4, lq = l & 15;
  int q0 = qt*64 + w*16;
  int rho = ((lq >> 2) << 3) + (lq & 3);        // 0-3,8-11,16-19,24-27
  bf16x8 qf = {};
  if (lg < 2) qf = *(const bf16x8*)&Qt[((size_t)bh*4096 + q0 + lq)*16 + lg*8];
  bf16x8 ones;
  #pragma unroll
  for (int j = 0; j < 8; ++j) ones[j] = (short)0x3F80;   // bf16 1.0
  f32x4 acc = {0.f, 0.f, 0.f, 0.f};
  f32x4 lacc = {0.f, 0.f, 0.f, 0.f};
  const hbf* Ktb = Kt + ((size_t)bh*4096 + c*1024)*16;
  const hbf* Vbb = Vb + (size_t)bh*16*4096 + c*1024;
  for (int kb = 0; kb < 1024; kb += 32){
    bf16x8 kf0 = {}, kf1 = {};
    if (lg < 2){
      kf0 = *(const bf16x8*)&Ktb[(size_t)(kb + rho)*16 + lg*8];
      kf1 = *(const bf16x8*)&Ktb[(size_t)(kb + rho + 4)*16 + lg*8];
    }
    f32x4 z = {0.f, 0.f, 0.f, 0.f};
    f32x4 s0 = __builtin_amdgcn_mfma_f32_16x16x32_bf16(kf0, qf, z, 0, 0, 0);
    f32x4 s1 = __builtin_amdgcn_mfma_f32_16x16x32_bf16(kf1, qf, z, 0, 0, 0);
    float p[8];
    p[0]=s0[0]; p[1]=s0[1]; p[2]=s0[2]; p[3]=s0[3];   // keys lg*8+0..3
    p[4]=s1[0]; p[5]=s1[1]; p[6]=s1[2]; p[7]=s1[3];   // keys lg*8+4..7
    #pragma unroll
    for (int i = 0; i < 8; ++i) p[i] = fexp2(p[i]);
    bf16x8 pf;
    #pragma unroll
    for (int j = 0; j < 8; ++j){
      hbf hb = __float2bfloat16(p[j]);
      pf[j] = *reinterpret_cast<short*>(&hb);
    }
    bf16x8 vf = *(const bf16x8*)&Vbb[(size_t)lq*4096 + kb + lg*8];
    acc  = __builtin_amdgcn_mfma_f32_16x16x32_bf16(vf, pf, acc, 0, 0, 0);
    lacc = __builtin_amdgcn_mfma_f32_16x16x32_bf16(ones, pf, lacc, 0, 0, 0);
  }
  float lsum = lacc[0];                 // all rows identical = per-query denominator
  int pb = c*8 + bh;
  if (lg == 0) Pl[(size_t)pb*4096 + q0 + lq] = lsum;
  #pragma unroll
  for (int r = 0; r < 4; ++r){
    int d = lg*4 + r;
    Pacc[((size_t)pb*16 + d)*4096 + q0 + lq] = acc[r];
  }
}

// ---------------------------------------------------------------- FFN dw3x3 + chunk + gelu gate (128->64)
__device__ __forceinline__ void dwgate_body(const float* __restrict__ in, const float* __restrict__ w,
                                            float* __restrict__ out, int g){
  int pix = g & 4095; int c = (g >> 12) & 63; int b = g >> 18;
  int y = pix >> 6, x = pix & 63;
  const float* p1 = in + ((size_t)b*128 + c)*NHW;
  const float* p2 = in + ((size_t)b*128 + 64 + c)*NHW;
  float w1[9], w2[9];
  #pragma unroll
  for (int i = 0; i < 9; ++i){ w1[i] = w[c*9+i]; w2[i] = w[(64+c)*9+i]; }
  float a = 0.f, bb = 0.f;
  #pragma unroll
  for (int ky = -1; ky <= 1; ++ky){
    int yy = y + ky; if ((unsigned)yy >= 64u) continue;
    #pragma unroll
    for (int kx = -1; kx <= 1; ++kx){
      int xx = x + kx; if ((unsigned)xx >= 64u) continue;
      int off = yy*64 + xx; int wi = (ky+1)*3 + (kx+1);
      a  += p1[off]*w1[wi];
      bb += p2[off]*w2[wi];
    }
  }
  float gl = 0.5f*a*(1.0f + erff(a*0.70710678118654752f));   // exact gelu
  out[g] = gl*bb;
}

__global__ __launch_bounds__(256) void k_dwgate(const float* __restrict__ in, const float* __restrict__ w,
                                                float* __restrict__ out){
  dwgate_body(in, w, out, blockIdx.x*256 + threadIdx.x);
}

// dwgate (spectral) || dw192 (restormer qkv) in one launch, scalar block split
__global__ __launch_bounds__(256) void k_dwg2(const float* __restrict__ inG, const float* __restrict__ wG,
                                              float* __restrict__ outG,
                                              const float* __restrict__ inD, const float* __restrict__ wD,
                                              float* __restrict__ outD){
  int bb = blockIdx.x;
  if (bb < SZ/256){
    dwgate_body(inG, wG, outG, bb*256 + threadIdx.x);
  } else {
    int g = (bb - SZ/256)*256 + threadIdx.x;    // B*192*4096
    int pix = g & 4095; int bc = g >> 12; int c = bc % 192;
    int y = pix >> 6, x = pix & 63;
    const float* p = inD + (size_t)bc*NHW;
    float wf[9];
    #pragma unroll
    for (int i = 0; i < 9; ++i) wf[i] = wD[c*9+i];
    float acc = 0.f;
    #pragma unroll
    for (int ky = -1; ky <= 1; ++ky){
      int yy = y + ky; if ((unsigned)yy >= 64u) continue;
      #pragma unroll
      for (int kx = -1; kx <= 1; ++kx){
        int xx = x + kx; if ((unsigned)xx >= 64u) continue;
        acc += p[yy*64 + xx]*wf[(ky+1)*3 + (kx+1)];
      }
    }
    outD[g] = acc;
  }
}

// ---------------------------------------------------------------- restormer channel attention
__global__ __launch_bounds__(256) void k_rattn2(const float* __restrict__ qkv, const float* __restrict__ norms,
                                                const float* __restrict__ temp, float* __restrict__ out){
  int blk = blockIdx.x; int rq = blk & 15, h = (blk >> 4) & 3, b = blk >> 6;
  int t = threadIdx.x;
  const float* bq = qkv + ((size_t)b*192 + h*16 + rq)*NHW;
  const float* bk = qkv + ((size_t)b*192 + 64 + h*16)*NHW;
  float p[16];
  #pragma unroll
  for (int rk = 0; rk < 16; ++rk) p[rk] = 0.f;
  for (int n = t*4; n < NHW; n += 1024){
    float4 qv4 = *(const float4*)(bq + n);
    #pragma unroll
    for (int rk = 0; rk < 16; ++rk){
      float4 kv = *(const float4*)(bk + (size_t)rk*NHW + n);
      p[rk] += qv4.x*kv.x + qv4.y*kv.y + qv4.z*kv.z + qv4.w*kv.w;
    }
  }
  #pragma unroll
  for (int rk = 0; rk < 16; ++rk)
    #pragma unroll
    for (int off = 32; off; off >>= 1) p[rk] += __shfl_xor(p[rk], off);
  __shared__ float red[4][16];
  if ((t & 63) == 0){
    int wv_ = t >> 6;
    #pragma unroll
    for (int rk = 0; rk < 16; ++rk) red[wv_][rk] = p[rk];
  }
  __syncthreads();
  __shared__ float attn[16];
  if (t == 0){
    float nq = norms[b*128 + h*16 + rq];
    float tp = temp[h];
    float e[16]; float mm = -1e30f;
    #pragma unroll
    for (int rk = 0; rk < 16; ++rk){
      float dot = red[0][rk]+red[1][rk]+red[2][rk]+red[3][rk];
      e[rk] = dot/(nq*norms[b*128 + 64 + h*16 + rk]) * tp;
      mm = fmaxf(mm, e[rk]);
    }
    float ssum = 0.f;
    #pragma unroll
    for (int rk = 0; rk < 16; ++rk){ e[rk] = __expf(e[rk]-mm); ssum += e[rk]; }
    float is = 1.f/ssum;
    #pragma unroll
    for (int rk = 0; rk < 16; ++rk) attn[rk] = e[rk]*is;
  }
  __syncthreads();
  float aw[16];
  #pragma unroll
  for (int rk = 0; rk < 16; ++rk) aw[rk] = attn[rk];
  const float* vb = qkv + ((size_t)b*192 + 128 + h*16)*NHW;
  float* ob = out + ((size_t)b*64 + h*16 + rq)*NHW;
  for (int n = t*4; n < NHW; n += 1024){
    float4 o; o.x = 0.f; o.y = 0.f; o.z = 0.f; o.w = 0.f;
    #pragma unroll
    for (int rk = 0; rk < 16; ++rk){
      float4 v = *(const float4*)(vb + (size_t)rk*NHW + n);
      o.x += aw[rk]*v.x; o.y += aw[rk]*v.y; o.z += aw[rk]*v.z; o.w += aw[rk]*v.w;
    }
    *(float4*)(ob + n) = o;
  }
}

// ================================================================ host
extern "C" void kernel_launch(void* const* d_in, const int* in_sizes, int n_in,
                              void* d_out, int out_size, void* d_ws, size_t ws_size,
                              hipStream_t stream){
  const float* hsi_f0     = (const float*)d_in[0];
  const float* msi_f0     = (const float*)d_in[1];
  const float* hsi_fi     = (const float*)d_in[2];
  const float* msi_fi     = (const float*)d_in[3];
  const float* sp_mlp_w   = (const float*)d_in[4];
  const float* sp_mlp_b   = (const float*)d_in[5];
  const float* spe_mlp_w  = (const float*)d_in[6];
  const float* spe_mlp_b  = (const float*)d_in[7];
  const float* spa_dw_w   = (const float*)d_in[8];
  const float* spa_dw_b   = (const float*)d_in[9];
  const float* spa_pw_w   = (const float*)d_in[10];
  const float* spa_pw_b   = (const float*)d_in[11];
  const float* spe_dw_w   = (const float*)d_in[12];
  const float* spe_dw_b   = (const float*)d_in[13];
  const float* spe_pw_w   = (const float*)d_in[14];
  const float* spe_pw_b   = (const float*)d_in[15];
  const float* sb_q_w     = (const float*)d_in[16];
  const float* sb_q_b     = (const float*)d_in[17];
  const float* sb_k_w     = (const float*)d_in[18];
  const float* sb_k_b     = (const float*)d_in[19];
  const float* sb_v_w     = (const float*)d_in[20];
  const float* sb_v_b     = (const float*)d_in[21];
  const float* sb_o_w     = (const float*)d_in[22];
  const float* sb_o_b     = (const float*)d_in[23];
  const float* sb_norm2_w = (const float*)d_in[24];
  const float* sb_ffn_in_w  = (const float*)d_in[25];
  const float* sb_ffn_dw_w  = (const float*)d_in[26];
  const float* sb_ffn_out_w = (const float*)d_in[27];
  const float* rb_norm1_w = (const float*)d_in[28];
  const float* rb_temp    = (const float*)d_in[29];
  const float* rb_qkv_w   = (const float*)d_in[30];
  const float* rb_qkv_dw_w= (const float*)d_in[31];
  const float* rb_proj_w  = (const float*)d_in[32];
  const float* rb_norm2_w = (const float*)d_in[33];
  const float* rb_ffn_in_w  = (const float*)d_in[34];
  const float* rb_ffn_dw_w  = (const float*)d_in[35];
  const float* rb_ffn_out_w = (const float*)d_in[36];

  float* W   = (float*)d_ws;
  float* Hb  = W;                 // hsi branch output      [B][64][HW]
  float* Mb  = W + (size_t)SZ;    // msi branch output; later: spectral gate G1
  float* Xb  = W + (size_t)2*SZ;  // x1
  float* Yb  = W + (size_t)3*SZ;  // y
  float* T1  = W + (size_t)4*SZ;  // dw-hsi out; QKV[0] later; rb gate out at end
  float* QKV = T1;                // 3*SZ contiguous (4SZ..7SZ) for restormer qkv
  float* TB  = W + (size_t)7*SZ;  // dw-msi out; 128-ch ffn buffer / attn out
  float* Tm  = TB;                // msi dw3 output (dead before TB reused)
  float* TB2 = W + (size_t)9*SZ;  // 3*SZ (192-ch pre-dw qkv)
  float* Pacc= W + (size_t)7*SZ;         // 4*SZ flash partial acc
  float* Pl  = W + (size_t)11*SZ;        // 131072
  float* mxb = W + (size_t)12*SZ;        // 128
  float* cmb = mxb + 256;                // 8192
  float* normb = W + (size_t)12*SZ + 9216; // 256
  // bf16 attention operand buffers in the 5SZ..7SZ region
  hbf* Qt  = (hbf*)(W + (size_t)5*SZ);            // [8][4096][16] bf16, pre-scaled 0.25*log2e
  hbf* Kt  = Qt + (size_t)8*4096*16;              // [8][4096][16]
  hbf* Vbf = Kt + (size_t)8*4096*16;              // [8][16][4096]
  float* G1 = Mb;                 // spectral gate output (Mb dead by then)

  float* outf = (float*)d_out;
  const float QS = 0.25f*LOG2E;

  // reductions (max-over-HW || channel-mean), one launch
  k_maxmean<<<NB*NC + NPIX/256, 256, 0, stream>>>(hsi_fi, mxb, msi_fi, cmb);
  // both depthwise branches + score MLPs, one launch
  k_dw3b<<<2*SZ/256, 256, 0, stream>>>(hsi_f0, spe_dw_w, spe_dw_b, mxb, spe_mlp_w, spe_mlp_b,
                                       msi_f0, spa_dw_w, spa_dw_b, cmb, sp_mlp_w, sp_mlp_b,
                                       T1, Tm);
  // branch 1x1 convs, one launch
  k_pwbr<<<dim3(NPIX/32,1,2), 256, 0, stream>>>(T1, spe_pw_w, spe_pw_b, Hb,
                                                Tm, spa_pw_w, spa_pw_b, Mb);
  // Q,K,V projections, one launch
  k_pwqkv<<<dim3(NPIX/32,1,3), 256, 0, stream>>>(Mb, Hb, sb_q_w, sb_q_b, sb_k_w, sb_k_b,
                                                 sb_v_w, sb_v_b, Qt, Kt, Vbf, QS);
  k_mfa<<<2048, 256, 0, stream>>>(Qt, Kt, Vbf, Pacc, Pl);
  // o-proj with fused no-max flash-combine input (+msi residual)
  k_pw<<<dim3(NPIX/32,1), 256, 0, stream>>>(nullptr, sb_o_w, sb_o_b, nullptr, nullptr, nullptr, Mb, nullptr, Xb, 64, Pacc, Pl);
  // spectral ffn_in (LN fused) || restormer qkv (y=Hb+Mb in-staging, LN fused), one launch
  k_pwfi<<<dim3(NPIX/32,3,2), 256, 0, stream>>>(Xb, sb_ffn_in_w, sb_norm2_w, TB,
                                                Hb, rb_qkv_w, rb_norm1_w, Mb, Yb, TB2);
  // spectral dw-gate || restormer qkv dw3x3 (gate out -> G1=Mb, now dead)
  k_dwg2<<<SZ/256 + 3*SZ/256, 256, 0, stream>>>(TB, sb_ffn_dw_w, G1, TB2, rb_qkv_dw_w, QKV);
  // spectral ffn_out (x1 = Xb + out) || restormer rnorm, one launch
  k_pwrn<<<NPIX/32 + 256, 256, 0, stream>>>(G1, sb_ffn_out_w, Xb, Xb, QKV, normb);
  // restormer attention
  k_rattn2<<<128, 256, 0, stream>>>(QKV, normb, rb_temp, TB);
  k_pw<<<dim3(NPIX/32,1), 256, 0, stream>>>(TB, rb_proj_w, nullptr, nullptr, nullptr, nullptr, Yb, nullptr, Yb, 64, nullptr, nullptr);
  // restormer FFN + final combine: out = x1 + (y + ffn(ln(y)))
  k_pw<<<dim3(NPIX/32,2), 256, 0, stream>>>(Yb, rb_ffn_in_w, nullptr, rb_norm2_w, nullptr, nullptr, nullptr, nullptr, TB, 128, nullptr, nullptr);
  k_dwgate<<<SZ/256, 256, 0, stream>>>(TB, rb_ffn_dw_w, T1);
  k_pw<<<dim3(NPIX/32,1), 256, 0, stream>>>(T1, rb_ffn_out_w, nullptr, nullptr, nullptr, nullptr, Xb, Yb, outf, 64, nullptr, nullptr);
}